// Round 4
// baseline (1555.525 us; speedup 1.0000x reference)
//
#include <hip/hip_runtime.h>

#define NN 50000
#define EE 800000
#define HH 128
#define GG 50
#define FF 128
#define SS 2
#define BB 256
#define SLOTW 8    // per-wave accW rows; slots >= cap go straight to global atomics (rare)

typedef short bf16x8 __attribute__((ext_vector_type(8)));
typedef float floatx4 __attribute__((ext_vector_type(4)));

union FragU { bf16x8 v; unsigned short u[8]; unsigned int d[4]; uint4 q; };

__device__ __forceinline__ float bf2f(unsigned short u) {
    union { unsigned int i; float f; } c; c.i = ((unsigned int)u) << 16; return c.f;
}
__device__ __forceinline__ unsigned short f2bf(float f) {
    union { float f; unsigned int i; } c; c.f = f;
    unsigned int i = c.i;
    unsigned int r = (i + 0x7fffu + ((i >> 16) & 1u)) >> 16;
    return (unsigned short)r;
}
__device__ __forceinline__ float sspf(float x) {
    float l = __logf(1.f + __expf(x));
    l = (x > 20.f) ? x : l;
    return l - 0.69314718056f;
}
__device__ __forceinline__ bf16x8 f8frag(const float* p) {       // fp32 -> bf16 frag
    FragU f;
#pragma unroll
    for (int j = 0; j < 8; j++) f.u[j] = f2bf(p[j]);
    return f.v;
}
__device__ __forceinline__ bf16x8 load16(const unsigned short* p) { // 16B-aligned bf16
    FragU f; f.q = *(const uint4*)p; return f.v;
}
__device__ __forceinline__ bf16x8 loaddw(const unsigned short* p) { // 4B-aligned bf16
    FragU f; const unsigned int* pp = (const unsigned int*)p;
#pragma unroll
    for (int t = 0; t < 4; t++) f.d[t] = pp[t];
    return f.v;
}
__device__ __forceinline__ int clampi(int v, int hi) {
    v = (v < 0) ? 0 : v;
    return (v > hi) ? hi : v;
}

// ---------------- kConv: fp32 -> bf16 bulk convert ----------------
__global__ __launch_bounds__(256) void kConv(const float* __restrict__ s,
                                             unsigned short* __restrict__ d, int n) {
    for (int i = blockIdx.x * 256 + threadIdx.x; i < n; i += gridDim.x * 256)
        d[i] = f2bf(s[i]);
}

// ---------------- kConvW: all weight arrays -> bf16 bank (+ K=64 zero-padded mlp_w1) ----------------
__global__ __launch_bounds__(256) void kConvW(const float* __restrict__ a0,  // mw1 12800
                                              const float* __restrict__ a1,  // mw2 32768
                                              const float* __restrict__ a2,  // c1w 32768
                                              const float* __restrict__ a3,  // c2w 32768
                                              const float* __restrict__ a4,  // lin1w 33280
                                              const float* __restrict__ a5,  // outw 16384
                                              unsigned short* __restrict__ d) {
    int i = blockIdx.x * 256 + threadIdx.x;   // grid covers 177152 exactly
    float v;
    if (i < 12800)        v = a0[i];
    else if (i < 45568)   v = a1[i - 12800];
    else if (i < 78336)   v = a2[i - 45568];
    else if (i < 111104)  v = a3[i - 78336];
    else if (i < 144384)  v = a4[i - 111104];
    else if (i < 160768)  v = a5[i - 144384];
    else {
        // padded mlp_w1: [2][128][64], zero beyond col 50
        int j = i - 160768;           // 0..16383
        int k = j & 63;
        int nl = j >> 6;              // layer*128 + n
        v = (k < 50) ? a0[nl * 50 + k] : 0.f;
    }
    d[i] = f2bf(v);
}

// ---------------- kPrep: batch histogram + state init ----------------
__global__ __launch_bounds__(256) void kPrep(const int* __restrict__ batch,
                                             int* __restrict__ counts,
                                             const float* __restrict__ sa_in,
                                             float* __restrict__ stateBuf) {
    int i = blockIdx.x * 256 + threadIdx.x;
    if (i < NN) atomicAdd(&counts[clampi(batch[i], BB - 1)], 1);
    if (i < BB * SS) stateBuf[i] = sa_in[i];
}

// ---------------- kHist: edges-per-dst histogram ----------------
__global__ __launch_bounds__(256) void kHist(const int* __restrict__ eidx,
                                             int* __restrict__ cnt) {
    for (int e = blockIdx.x * 256 + threadIdx.x; e < EE; e += gridDim.x * 256)
        atomicAdd(&cnt[clampi(eidx[EE + e], NN - 1)], 1);
}

// ---------------- 3-phase multi-block exclusive scan ----------------
__global__ __launch_bounds__(1024) void kScanA(const int* __restrict__ cnt,
                                               int* __restrict__ off,
                                               int* __restrict__ blkSum) {
    __shared__ int s[1024];
    int tid = threadIdx.x;
    int g = blockIdx.x * 1024 + tid;
    int v = (g < NN) ? cnt[g] : 0;
    s[tid] = v;
    __syncthreads();
#pragma unroll
    for (int o = 1; o < 1024; o <<= 1) {
        int x = (tid >= o) ? s[tid - o] : 0;
        __syncthreads();
        s[tid] += x;
        __syncthreads();
    }
    if (g < NN) off[g] = s[tid] - v;
    if (tid == 1023) blkSum[blockIdx.x] = s[1023];
}
__global__ void kScanB(int* __restrict__ blkSum, int nb) {
    if (threadIdx.x == 0) {
        int acc = 0;
        for (int i = 0; i < nb; i++) { int t = blkSum[i]; blkSum[i] = acc; acc += t; }
    }
}
__global__ __launch_bounds__(256) void kScanC(int* __restrict__ off,
                                              const int* __restrict__ blkSum) {
    int g = blockIdx.x * 256 + threadIdx.x;
    if (g < NN) off[g] += blkSum[g >> 10];
}

// ---------------- kScatter: pos[e] + sorted dst/src/C arrays ----------------
__global__ __launch_bounds__(256) void kScatter(const int* __restrict__ eidx,
                                                const float* __restrict__ ew,
                                                const int* __restrict__ off,
                                                int* __restrict__ cur,
                                                int* __restrict__ pos,
                                                int* __restrict__ ePerm,
                                                int* __restrict__ dstS,
                                                int* __restrict__ srcS,
                                                float* __restrict__ cS) {
    for (int e = blockIdx.x * 256 + threadIdx.x; e < EE; e += gridDim.x * 256) {
        int d = clampi(eidx[EE + e], NN - 1);
        int p = off[d] + atomicAdd(&cur[d], 1);
        pos[e] = p;
        ePerm[p] = e;
        dstS[p] = d;
        srcS[p] = clampi(eidx[e], NN - 1);
        float w = ew[e];
        cS[p] = 0.5f * (__cosf(w * 0.62831853072f) + 1.f);
    }
}

// ---------------- kPermEA: edge_attr -> sorted order, bf16, K zero-padded 50->64 ----------------
__global__ __launch_bounds__(256) void kPermEA(const float* __restrict__ ea,
                                               const int* __restrict__ pos,
                                               unsigned short* __restrict__ eaSb) {
    int idx = blockIdx.x * 256 + threadIdx.x;   // grid covers EE*4 exactly
    int e = idx >> 2, part = idx & 3;
    int p = pos[e];
    const float* src = ea + (size_t)e * 50 + part * 16;
    FragU f0, f1;
#pragma unroll
    for (int j = 0; j < 8; j++) f0.u[j] = (part * 16 + j < 50) ? f2bf(src[j]) : 0;
#pragma unroll
    for (int j = 0; j < 8; j++) f1.u[j] = (part * 16 + 8 + j < 50) ? f2bf(src[8 + j]) : 0;
    uint4* d = (uint4*)(eaSb + (size_t)p * 64 + part * 16);
    d[0] = f0.q; d[1] = f1.q;
}

// ---------------- kA: h2 = lin1([sa,h]) ; xf = conv_lin1(h2) ----------------
__global__ __launch_bounds__(256) void kA(const unsigned short* __restrict__ hb,   // [N,128] bf16
                                          const unsigned short* __restrict__ l1wb, // [128,130] bf16
                                          const float* __restrict__ lin1w,         // [128,130] fp32
                                          const float* __restrict__ lin1b,
                                          const unsigned short* __restrict__ c1wb, // [128,128] bf16
                                          const float* __restrict__ stateBuf,
                                          const int* __restrict__ batch,
                                          unsigned short* __restrict__ h2b,        // [N,128] bf16
                                          unsigned short* __restrict__ xfb) {      // [N,128] bf16
    __shared__ __align__(16) unsigned short P[64][136];
    int lane = threadIdx.x & 63;
    int wave = threadIdx.x >> 6;
    int m = lane & 15, q = lane >> 4;
    int rowBase = blockIdx.x * 64 + wave * 16;
    int arow = rowBase + m;
    int arowc = (arow < NN) ? arow : (NN - 1);

    floatx4 acc[8];
#pragma unroll
    for (int t = 0; t < 8; t++) acc[t] = (floatx4){0.f, 0.f, 0.f, 0.f};

#pragma unroll
    for (int k0 = 0; k0 < 128; k0 += 32) {
        bf16x8 a = load16(hb + (size_t)arowc * 128 + k0 + q * 8);
#pragma unroll
        for (int t = 0; t < 8; t++) {
            int n = t * 16 + m;
            bf16x8 b = loaddw(l1wb + (size_t)n * 130 + 2 + k0 + q * 8);
            acc[t] = __builtin_amdgcn_mfma_f32_16x16x32_bf16(a, b, acc[t], 0, 0, 0);
        }
    }

    int r0 = rowBase + q * 4;
    float s0[4], s1[4];
#pragma unroll
    for (int j = 0; j < 4; j++) {
        int r = r0 + j; int rc = (r < NN) ? r : (NN - 1);
        int g = clampi(batch[rc], BB - 1);
        s0[j] = stateBuf[g * 2 + 0];
        s1[j] = stateBuf[g * 2 + 1];
    }
#pragma unroll
    for (int t = 0; t < 8; t++) {
        int c = t * 16 + m;
        float w0 = lin1w[(size_t)c * 130 + 0];
        float w1 = lin1w[(size_t)c * 130 + 1];
        float bb = lin1b[c];
#pragma unroll
        for (int j = 0; j < 4; j++) {
            int r = r0 + j;
            unsigned short vb = f2bf(acc[t][j] + bb + s0[j] * w0 + s1[j] * w1);
            if (r < NN) h2b[(size_t)r * 128 + c] = vb;
            P[wave * 16 + q * 4 + j][c] = vb;
        }
    }
    __syncthreads();

    floatx4 acc2[8];
#pragma unroll
    for (int t = 0; t < 8; t++) acc2[t] = (floatx4){0.f, 0.f, 0.f, 0.f};
#pragma unroll
    for (int k0 = 0; k0 < 128; k0 += 32) {
        FragU fa; fa.q = *(const uint4*)&P[wave * 16 + m][k0 + q * 8];
#pragma unroll
        for (int t = 0; t < 8; t++) {
            int n = t * 16 + m;
            bf16x8 b = load16(c1wb + (size_t)n * 128 + k0 + q * 8);
            acc2[t] = __builtin_amdgcn_mfma_f32_16x16x32_bf16(fa.v, b, acc2[t], 0, 0, 0);
        }
    }
#pragma unroll
    for (int t = 0; t < 8; t++) {
        int c = t * 16 + m;
#pragma unroll
        for (int j = 0; j < 4; j++) {
            int r = r0 + j;
            if (r < NN) xfb[(size_t)r * 128 + c] = f2bf(acc2[t][j]);
        }
    }
}

// ---------------- kF: barrier-free fused edge kernel ----------------
// 4 independent wave-private 16-edge tiles per block; zero __syncthreads.
// Slot math fully in registers (ballot+popc); P/accW are per-wave LDS slices.
// Same-wave LDS RAW ordering is guaranteed by the in-order DS pipe.
__global__ __launch_bounds__(256) void kF(const unsigned short* __restrict__ eaSb, // [E,64] bf16 sorted
                                          const unsigned short* __restrict__ w1pb, // [128,64] bf16 padded
                                          const float* __restrict__ b1,
                                          const unsigned short* __restrict__ w2b,  // [128,128] bf16
                                          const float* __restrict__ b2,
                                          const int* __restrict__ dstS,
                                          const int* __restrict__ srcS,
                                          const float* __restrict__ cS,
                                          const unsigned short* __restrict__ xfb,
                                          float* __restrict__ agg) {
    __shared__ __align__(16) unsigned short P[4][16][136];  // per-wave hidden, then xf rows
    __shared__ float accW[4][SLOTW][132];                   // per-wave dst accumulators
    __shared__ int slotDst[4][16];

    int tid = threadIdx.x;
    int lane = tid & 63;
    int w = tid >> 6;
    int m = lane & 15, q = lane >> 4;
    int base = (blockIdx.x * 4 + w) * 16;    // this wave's 16-edge tile

    // --- issue all long-latency loads up front ---
    // xf-row gathers: 4 lanes per edge row, 64B each
    int gr = lane >> 2, gc = lane & 3;
    int gsrc = srcS[base + gr];
    const uint4* gs = (const uint4*)&xfb[(size_t)gsrc * 128 + gc * 32];
    uint4 x0 = gs[0], x1 = gs[1], x2 = gs[2], x3 = gs[3];

    // eaSb A-frags (HBM stream)
    int eRow = base + m;
    bf16x8 a0 = load16(eaSb + (size_t)eRow * 64 + 0  + q * 8);
    bf16x8 a1 = load16(eaSb + (size_t)eRow * 64 + 32 + q * 8);

    // --- slot/run computation, register-only ---
    int d_r = dstS[base + m];
    int dp = __shfl(d_r, (lane - 1) & 63);   // lane-1 holds row m-1 within each q-group
    bool flag = (m == 0) || (d_r != dp);
    unsigned long long bm = __ballot(flag ? 1 : 0);
    unsigned int bmlow = (unsigned int)(bm & 0xFFFFull);   // rows 0..15 (q=0 group)
    int D = __popc(bmlow);
    int Dc = (D < SLOTW) ? D : SLOTW;
    {
        int slot_m = __popc(bmlow & ((2u << m) - 1u)) - 1;
        if (lane < 16 && flag) slotDst[w][slot_m] = d_r;
    }
    float Cj[4]; int sl[4];
#pragma unroll
    for (int j = 0; j < 4; j++) {
        int r = q * 4 + j;
        Cj[j] = cS[base + r];
        sl[j] = __popc(bmlow & ((2u << r) - 1u)) - 1;
    }

    // zero live accW rows (wave-private)
    {
        float* fl = &accW[w][0][0];
        for (int i = lane; i < Dc * 132; i += 64) fl[i] = 0.f;
    }

    // --- GEMM1: eaSb @ w1p^T (K=64) ---
    floatx4 acc[8];
#pragma unroll
    for (int t = 0; t < 8; t++) acc[t] = (floatx4){0.f, 0.f, 0.f, 0.f};
#pragma unroll
    for (int t = 0; t < 8; t++) {
        int n = t * 16 + m;
        bf16x8 b = load16(w1pb + (size_t)n * 64 + 0 + q * 8);
        acc[t] = __builtin_amdgcn_mfma_f32_16x16x32_bf16(a0, b, acc[t], 0, 0, 0);
    }
#pragma unroll
    for (int t = 0; t < 8; t++) {
        int n = t * 16 + m;
        bf16x8 b = load16(w1pb + (size_t)n * 64 + 32 + q * 8);
        acc[t] = __builtin_amdgcn_mfma_f32_16x16x32_bf16(a1, b, acc[t], 0, 0, 0);
    }
#pragma unroll
    for (int t = 0; t < 8; t++) {
        int c = t * 16 + m;
        float bb = b1[c];
#pragma unroll
        for (int j = 0; j < 4; j++)
            P[w][q * 4 + j][c] = f2bf(sspf(acc[t][j] + bb));
    }

    // --- GEMM2: P @ w2^T (in-wave LDS dep; DS pipe is in-order per wave) ---
    floatx4 acc2[8];
#pragma unroll
    for (int t = 0; t < 8; t++) acc2[t] = (floatx4){0.f, 0.f, 0.f, 0.f};
#pragma unroll
    for (int k0 = 0; k0 < 128; k0 += 32) {
        FragU fa; fa.q = *(const uint4*)&P[w][m][k0 + q * 8];
#pragma unroll
        for (int t = 0; t < 8; t++) {
            int n = t * 16 + m;
            bf16x8 b = load16(w2b + (size_t)n * 128 + k0 + q * 8);
            acc2[t] = __builtin_amdgcn_mfma_f32_16x16x32_bf16(fa.v, b, acc2[t], 0, 0, 0);
        }
    }

    // park staged xf rows in P (after this wave's GEMM2 reads)
    {
        uint4* dptr = (uint4*)&P[w][gr][gc * 32];
        dptr[0] = x0; dptr[1] = x1; dptr[2] = x2; dptr[3] = x3;
    }

    // --- epilogue: msg = (eh + b2) * C * xf[src], run-combine by dst slot ---
#pragma unroll
    for (int t = 0; t < 8; t++) {
        int c = t * 16 + m;
        float bb = b2[c];
        float v4[4];
#pragma unroll
        for (int j = 0; j < 4; j++)
            v4[j] = (acc2[t][j] + bb) * Cj[j] * bf2f(P[w][q * 4 + j][c]);
        float run = v4[0];
#pragma unroll
        for (int j = 1; j < 4; j++) {
            if (sl[j] == sl[j - 1]) run += v4[j];
            else {
                int s = sl[j - 1];
                if (s < SLOTW) atomicAdd(&accW[w][s][c], run);
                else unsafeAtomicAdd(&agg[(size_t)slotDst[w][s] * 128 + c], run);
                run = v4[j];
            }
        }
        {
            int s = sl[3];
            if (s < SLOTW) atomicAdd(&accW[w][s][c], run);
            else unsafeAtomicAdd(&agg[(size_t)slotDst[w][s] * 128 + c], run);
        }
    }

    // --- flush: interior slots fully owned -> plain store; boundary -> atomic ---
    for (int i = lane; i < Dc * 128; i += 64) {
        int s = i >> 7, cc = i & 127;
        float v = accW[w][s][cc];
        size_t o = (size_t)slotDst[w][s] * 128 + cc;
        if (s > 0 && s < D - 1) agg[o] = v;
        else unsafeAtomicAdd(&agg[o], v);
    }
}

// ---------------- kE2 (fallback when workspace too small for eaSb) ----------------
__global__ __launch_bounds__(256) void kE2(const float* __restrict__ ea,
                                           const unsigned short* __restrict__ w1b,
                                           const float* __restrict__ b1,
                                           const unsigned short* __restrict__ w2b,
                                           const float* __restrict__ b2,
                                           const int* __restrict__ ePerm,
                                           const int* __restrict__ dstS,
                                           const int* __restrict__ srcS,
                                           const float* __restrict__ cS,
                                           const unsigned short* __restrict__ xfb,
                                           float* __restrict__ agg) {
    __shared__ __align__(16) unsigned short P[64][136];
    __shared__ float accS[64][132];
    __shared__ int sSlot[64];
    __shared__ int sSlotDst[64];
    __shared__ int sD;

    int tid = threadIdx.x;
    int lane = tid & 63;
    int wave = tid >> 6;
    int m = lane & 15, q = lane >> 4;
    int base = blockIdx.x * 64;

    float* accFlat = &accS[0][0];
    for (int i = tid; i < 64 * 132; i += 256) accFlat[i] = 0.f;

    if (tid < 64) {
        int i = tid;
        int di = dstS[base + i];
        bool flag = (i == 0) || (di != dstS[base + i - 1]);
        unsigned long long bm = __ballot(flag ? 1 : 0);
        unsigned long long low = (i == 63) ? ~0ull : ((1ull << (i + 1)) - 1ull);
        int slot = (int)__popcll(bm & low) - 1;
        sSlot[i] = slot;
        if (flag) sSlotDst[slot] = di;
        if (i == 63) sD = slot + 1;
    }

    int eRow = ePerm[base + wave * 16 + m];

    floatx4 acc[8];
#pragma unroll
    for (int t = 0; t < 8; t++) acc[t] = (floatx4){0.f, 0.f, 0.f, 0.f};
    {
        bf16x8 a = f8frag(ea + (size_t)eRow * 50 + q * 8);
#pragma unroll
        for (int t = 0; t < 8; t++) {
            int n = t * 16 + m;
            bf16x8 b = loaddw(w1b + (size_t)n * 50 + q * 8);
            acc[t] = __builtin_amdgcn_mfma_f32_16x16x32_bf16(a, b, acc[t], 0, 0, 0);
        }
    }
    {
        int kbase = 32 + q * 8;
        FragU fa;
        const float* pa = ea + (size_t)eRow * 50 + kbase;
#pragma unroll
        for (int j = 0; j < 8; j++) fa.u[j] = (kbase + j < 50) ? f2bf(pa[j]) : 0;
#pragma unroll
        for (int t = 0; t < 8; t++) {
            int n = t * 16 + m;
            FragU fb;
            const unsigned int* pb = (const unsigned int*)(w1b + (size_t)n * 50 + kbase);
#pragma unroll
            for (int t2 = 0; t2 < 4; t2++) fb.d[t2] = (kbase + 2 * t2 < 50) ? pb[t2] : 0u;
            acc[t] = __builtin_amdgcn_mfma_f32_16x16x32_bf16(fa.v, fb.v, acc[t], 0, 0, 0);
        }
    }
#pragma unroll
    for (int t = 0; t < 8; t++) {
        int c = t * 16 + m;
        float bb = b1[c];
#pragma unroll
        for (int j = 0; j < 4; j++)
            P[wave * 16 + q * 4 + j][c] = f2bf(sspf(acc[t][j] + bb));
    }
    __syncthreads();

    floatx4 acc2[8];
#pragma unroll
    for (int t = 0; t < 8; t++) acc2[t] = (floatx4){0.f, 0.f, 0.f, 0.f};
#pragma unroll
    for (int k0 = 0; k0 < 128; k0 += 32) {
        FragU fa; fa.q = *(const uint4*)&P[wave * 16 + m][k0 + q * 8];
#pragma unroll
        for (int t = 0; t < 8; t++) {
            int n = t * 16 + m;
            bf16x8 b = load16(w2b + (size_t)n * 128 + k0 + q * 8);
            acc2[t] = __builtin_amdgcn_mfma_f32_16x16x32_bf16(fa.v, b, acc2[t], 0, 0, 0);
        }
    }

    int sl[4], srcj[4]; float Cj[4];
#pragma unroll
    for (int j = 0; j < 4; j++) {
        int r = wave * 16 + q * 4 + j;
        int g = base + r;
        sl[j] = sSlot[r];
        Cj[j] = cS[g];
        srcj[j] = srcS[g];
    }
#pragma unroll
    for (int t = 0; t < 8; t++) {
        int c = t * 16 + m;
        float bb = b2[c];
        float v4[4];
#pragma unroll
        for (int j = 0; j < 4; j++)
            v4[j] = (acc2[t][j] + bb) * Cj[j] * bf2f(xfb[(size_t)srcj[j] * 128 + c]);
        float run = v4[0];
#pragma unroll
        for (int j = 1; j < 4; j++) {
            if (sl[j] == sl[j - 1]) run += v4[j];
            else { atomicAdd(&accS[sl[j - 1]][c], run); run = v4[j]; }
        }
        atomicAdd(&accS[sl[3]][c], run);
    }
    __syncthreads();

    int D = sD;
    for (int idx = tid; idx < D * 128; idx += 256) {
        int s = idx >> 7, c = idx & 127;
        unsafeAtomicAdd(&agg[(size_t)sSlotDst[s] * 128 + c], accS[s][c]);
    }
}

// ---------------- kC: xc = conv_lin2(agg); h = h2 + ssp(xc); pooling ----------------
__global__ __launch_bounds__(256) void kC(const float* __restrict__ agg,
                                          const unsigned short* __restrict__ wb,
                                          const float* __restrict__ b,
                                          const unsigned short* __restrict__ h2b,
                                          unsigned short* __restrict__ hnb,
                                          const int* __restrict__ batch,
                                          float* __restrict__ pool,
                                          int doPool) {
    int lane = threadIdx.x & 63;
    int wave = threadIdx.x >> 6;
    int m = lane & 15, q = lane >> 4;
    int rowBase = blockIdx.x * 64 + wave * 16;
    int arow = rowBase + m;
    int arowc = (arow < NN) ? arow : (NN - 1);

    floatx4 acc[8];
#pragma unroll
    for (int t = 0; t < 8; t++) acc[t] = (floatx4){0.f, 0.f, 0.f, 0.f};

#pragma unroll
    for (int k0 = 0; k0 < 128; k0 += 32) {
        bf16x8 fa = f8frag(agg + (size_t)arowc * 128 + k0 + q * 8);
#pragma unroll
        for (int t = 0; t < 8; t++) {
            int n = t * 16 + m;
            bf16x8 bfr = load16(wb + (size_t)n * 128 + k0 + q * 8);
            acc[t] = __builtin_amdgcn_mfma_f32_16x16x32_bf16(fa, bfr, acc[t], 0, 0, 0);
        }
    }

    int r0 = rowBase + q * 4;
    float vsum[4] = {0.f, 0.f, 0.f, 0.f};
#pragma unroll
    for (int t = 0; t < 8; t++) {
        int c = t * 16 + m;
        float bb = b[c];
#pragma unroll
        for (int j = 0; j < 4; j++) {
            int r = r0 + j; int rc = (r < NN) ? r : (NN - 1);
            float v = bf2f(h2b[(size_t)rc * 128 + c]) + sspf(acc[t][j] + bb);
            if (r < NN) {
                hnb[(size_t)r * 128 + c] = f2bf(v);
                vsum[j] += v;
            }
        }
    }
    if (doPool) {
#pragma unroll
        for (int j = 0; j < 4; j++) {
            float v = vsum[j];
#pragma unroll
            for (int off = 1; off < 16; off <<= 1) v += __shfl_xor(v, off, 16);
            int r = r0 + j;
            if (m == 0 && r < NN) unsafeAtomicAdd(&pool[clampi(batch[r], BB - 1)], v);
        }
    }
}

// ---------------- kS ----------------
__global__ __launch_bounds__(256) void kS(const float* __restrict__ pool,
                                          const int* __restrict__ counts,
                                          float* __restrict__ stateBuf) {
    int b = threadIdx.x;
    if (b < BB) {
        float c = (float)counts[b];
        c = (c < 1.f) ? 1.f : c;
        float v = pool[b] / c;
        stateBuf[b * 2 + 0] = v;
        stateBuf[b * 2 + 1] = v;
    }
}

// ---------------- kOut ----------------
__global__ __launch_bounds__(256) void kOut(const unsigned short* __restrict__ hnb,
                                            const unsigned short* __restrict__ owb,
                                            const float* __restrict__ ob,
                                            float* __restrict__ out) {
    int lane = threadIdx.x & 63;
    int wave = threadIdx.x >> 6;
    int m = lane & 15, q = lane >> 4;
    int rowBase = blockIdx.x * 64 + wave * 16;
    int arow = rowBase + m;
    int arowc = (arow < NN) ? arow : (NN - 1);

    floatx4 acc[8];
#pragma unroll
    for (int t = 0; t < 8; t++) acc[t] = (floatx4){0.f, 0.f, 0.f, 0.f};
#pragma unroll
    for (int k0 = 0; k0 < 128; k0 += 32) {
        bf16x8 a = load16(hnb + (size_t)arowc * 128 + k0 + q * 8);
#pragma unroll
        for (int t = 0; t < 8; t++) {
            int n = t * 16 + m;
            bf16x8 bfr = load16(owb + (size_t)n * 128 + k0 + q * 8);
            acc[t] = __builtin_amdgcn_mfma_f32_16x16x32_bf16(a, bfr, acc[t], 0, 0, 0);
        }
    }
    int r0 = rowBase + q * 4;
#pragma unroll
    for (int t = 0; t < 8; t++) {
        int c = t * 16 + m;
        float bb = ob[c];
#pragma unroll
        for (int j = 0; j < 4; j++) {
            int r = r0 + j;
            if (r < NN) out[(size_t)r * 128 + c] = acc[t][j] + bb;
        }
    }
}

extern "C" void kernel_launch(void* const* d_in, const int* in_sizes, int n_in,
                              void* d_out, int out_size, void* d_ws, size_t ws_size,
                              hipStream_t stream) {
    const float* h     = (const float*)d_in[0];
    const float* ew    = (const float*)d_in[1];
    const float* ea    = (const float*)d_in[2];
    const float* sa    = (const float*)d_in[3];
    const float* lin1w = (const float*)d_in[4];
    const float* lin1b = (const float*)d_in[5];
    const float* mw1   = (const float*)d_in[6];
    const float* mb1   = (const float*)d_in[7];
    const float* mw2   = (const float*)d_in[8];
    const float* mb2   = (const float*)d_in[9];
    const float* c1w   = (const float*)d_in[10];
    const float* c2w   = (const float*)d_in[11];
    const float* c2b   = (const float*)d_in[12];
    const float* outw  = (const float*)d_in[13];
    const float* outb  = (const float*)d_in[14];
    const int* eidx    = (const int*)d_in[15];
    const int* batch   = (const int*)d_in[16];
    float* out = (float*)d_out;

    char* ws = (char*)d_ws;
    unsigned short* hnb   = (unsigned short*)(ws);              // 12.8 MB
    unsigned short* h2b   = (unsigned short*)(ws + 12800000);   // 12.8 MB
    unsigned short* xfb   = (unsigned short*)(ws + 25600000);   // 12.8 MB
    float*          agg   = (float*)(ws + 38400000);            // 25.6 MB
    int*            pos   = (int*)(ws + 64000000);              // 3.2 MB
    int*            ePerm = (int*)(ws + 67200000);              // 3.2 MB (fallback only)
    int*            dstS  = (int*)(ws + 70400000);              // 3.2 MB
    int*            srcS  = (int*)(ws + 73600000);              // 3.2 MB
    float*          cS    = (float*)(ws + 76800000);            // 3.2 MB
    int*            cnt   = (int*)(ws + 80000000);              // 200 KB
    int*            off   = (int*)(ws + 80200000);              // 200 KB
    int*            cur   = (int*)(ws + 80400000);              // 200 KB
    int*            blkSum= (int*)(ws + 80600000);              // 256 B
    unsigned short* wb    = (unsigned short*)(ws + 80600512);   // 354,304 B (177152 ushorts)
    float*          pool  = (float*)(ws + 80954816);
    int*            counts= (int*)(ws + 80955840);
    float*          stateBuf = (float*)(ws + 80956864);
    const size_t EAOFF = 80958912;                              // 16B aligned
    unsigned short* eaSb = (unsigned short*)(ws + EAOFF);       // 102.4 MB

    const size_t need = EAOFF + (size_t)EE * 64 * 2;
    const int useF = (ws_size >= need) ? 1 : 0;

    // bf16 weight banks
    unsigned short* mw1b = wb;            // [2][128][50]   (fallback kE2)
    unsigned short* mw2b = wb + 12800;    // [2][128][128]
    unsigned short* c1wb = wb + 45568;    // [2][128][128]
    unsigned short* c2wb = wb + 78336;    // [2][128][128]
    unsigned short* l1wb = wb + 111104;   // [2][128][130]
    unsigned short* owb  = wb + 144384;   // [128][128]
    unsigned short* w1pb = wb + 160768;   // [2][128][64]  zero-padded mlp_w1

    hipMemsetAsync(cnt, 0, NN * 4, stream);
    hipMemsetAsync(cur, 0, NN * 4, stream);
    hipMemsetAsync(counts, 0, BB * 4, stream);
    hipMemsetAsync(pool, 0, BB * 4, stream);

    kPrep<<<(NN + 255) / 256, 256, 0, stream>>>(batch, counts, sa, stateBuf);
    kHist<<<1024, 256, 0, stream>>>(eidx, cnt);
    kScanA<<<(NN + 1023) / 1024, 1024, 0, stream>>>(cnt, off, blkSum);
    kScanB<<<1, 64, 0, stream>>>(blkSum, (NN + 1023) / 1024);
    kScanC<<<(NN + 255) / 256, 256, 0, stream>>>(off, blkSum);
    kScatter<<<1024, 256, 0, stream>>>(eidx, ew, off, cur, pos, ePerm, dstS, srcS, cS);

    kConvW<<<177152 / 256, 256, 0, stream>>>(mw1, mw2, c1w, c2w, lin1w, outw, wb);
    kConv<<<4096, 256, 0, stream>>>(h, hnb, NN * 128);
    if (useF) {
        kPermEA<<<(EE * 4) / 256, 256, 0, stream>>>(ea, pos, eaSb);   // once: ea constant over layers
    }

    const int gridN = (NN + 63) / 64;   // 782
    const int gridE = EE / 64;          // 12500 (kF: 4 wave-tiles of 16 edges per block)

    for (int i = 0; i < 2; i++) {
        hipMemsetAsync(agg, 0, (size_t)NN * 128 * 4, stream);
        kA<<<gridN, 256, 0, stream>>>(hnb,
                                      l1wb + (size_t)i * 128 * 130,
                                      lin1w + (size_t)i * 128 * 130,
                                      lin1b + (size_t)i * 128,
                                      c1wb + (size_t)i * 128 * 128,
                                      stateBuf, batch, h2b, xfb);
        if (useF) {
            kF<<<gridE, 256, 0, stream>>>(eaSb,
                                          w1pb + (size_t)i * 128 * 64,
                                          mb1 + (size_t)i * 128,
                                          mw2b + (size_t)i * 128 * 128,
                                          mb2 + (size_t)i * 128,
                                          dstS, srcS, cS, xfb, agg);
        } else {
            kE2<<<gridE, 256, 0, stream>>>(ea,
                                           mw1b + (size_t)i * 128 * 50,
                                           mb1 + (size_t)i * 128,
                                           mw2b + (size_t)i * 128 * 128,
                                           mb2 + (size_t)i * 128,
                                           ePerm, dstS, srcS, cS, xfb, agg);
        }
        kC<<<gridN, 256, 0, stream>>>(agg,
                                      c2wb + (size_t)i * 128 * 128,
                                      c2b + (size_t)i * 128,
                                      h2b, hnb, batch, pool, (i == 0) ? 1 : 0);
        if (i == 0) kS<<<1, 256, 0, stream>>>(pool, counts, stateBuf);
    }
    kOut<<<gridN, 256, 0, stream>>>(hnb, owb, outb, out);
}

// Round 6
// 1288.947 us; speedup vs baseline: 1.2068x; 1.2068x over previous
//
#include <hip/hip_runtime.h>

#define NN 50000
#define EE 800000
#define HH 128
#define GG 50
#define FF 128
#define SS 2
#define BB 256
#define SLOTW 4        // per-wave accW rows; slots >= cap go straight to global atomics (rare)
#define KFBLK 500      // kF grid: 500 blocks x 4 waves x 25 subtiles x 16 edges = 800000
#define NTPW 25        // sub-tiles per wave

typedef short bf16x8 __attribute__((ext_vector_type(8)));
typedef float floatx4 __attribute__((ext_vector_type(4)));

union FragU { bf16x8 v; unsigned short u[8]; unsigned int d[4]; uint4 q; };

__device__ __forceinline__ float bf2f(unsigned short u) {
    union { unsigned int i; float f; } c; c.i = ((unsigned int)u) << 16; return c.f;
}
__device__ __forceinline__ unsigned short f2bf(float f) {
    union { float f; unsigned int i; } c; c.f = f;
    unsigned int i = c.i;
    unsigned int r = (i + 0x7fffu + ((i >> 16) & 1u)) >> 16;
    return (unsigned short)r;
}
__device__ __forceinline__ float sspf(float x) {
    float l = __logf(1.f + __expf(x));
    l = (x > 20.f) ? x : l;
    return l - 0.69314718056f;
}
__device__ __forceinline__ bf16x8 f8frag(const float* p) {       // fp32 -> bf16 frag
    FragU f;
#pragma unroll
    for (int j = 0; j < 8; j++) f.u[j] = f2bf(p[j]);
    return f.v;
}
__device__ __forceinline__ bf16x8 load16(const unsigned short* p) { // 16B-aligned bf16
    FragU f; f.q = *(const uint4*)p; return f.v;
}
__device__ __forceinline__ bf16x8 loaddw(const unsigned short* p) { // 4B-aligned bf16
    FragU f; const unsigned int* pp = (const unsigned int*)p;
#pragma unroll
    for (int t = 0; t < 4; t++) f.d[t] = pp[t];
    return f.v;
}
__device__ __forceinline__ int clampi(int v, int hi) {
    v = (v < 0) ? 0 : v;
    return (v > hi) ? hi : v;
}

// ---------------- kConv: fp32 -> bf16 bulk convert ----------------
__global__ __launch_bounds__(256) void kConv(const float* __restrict__ s,
                                             unsigned short* __restrict__ d, int n) {
    for (int i = blockIdx.x * 256 + threadIdx.x; i < n; i += gridDim.x * 256)
        d[i] = f2bf(s[i]);
}

// ---------------- kConvW: all weight arrays -> bf16 bank (+ K=64 zero-padded mlp_w1) ----------------
__global__ __launch_bounds__(256) void kConvW(const float* __restrict__ a0,  // mw1 12800
                                              const float* __restrict__ a1,  // mw2 32768
                                              const float* __restrict__ a2,  // c1w 32768
                                              const float* __restrict__ a3,  // c2w 32768
                                              const float* __restrict__ a4,  // lin1w 33280
                                              const float* __restrict__ a5,  // outw 16384
                                              unsigned short* __restrict__ d) {
    int i = blockIdx.x * 256 + threadIdx.x;   // grid covers 177152 exactly
    float v;
    if (i < 12800)        v = a0[i];
    else if (i < 45568)   v = a1[i - 12800];
    else if (i < 78336)   v = a2[i - 45568];
    else if (i < 111104)  v = a3[i - 78336];
    else if (i < 144384)  v = a4[i - 111104];
    else if (i < 160768)  v = a5[i - 144384];
    else {
        // padded mlp_w1: [2][128][64], zero beyond col 50
        int j = i - 160768;           // 0..16383
        int k = j & 63;
        int nl = j >> 6;              // layer*128 + n
        v = (k < 50) ? a0[nl * 50 + k] : 0.f;
    }
    d[i] = f2bf(v);
}

// ---------------- kPrep: batch histogram + state init ----------------
__global__ __launch_bounds__(256) void kPrep(const int* __restrict__ batch,
                                             int* __restrict__ counts,
                                             const float* __restrict__ sa_in,
                                             float* __restrict__ stateBuf) {
    int i = blockIdx.x * 256 + threadIdx.x;
    if (i < NN) atomicAdd(&counts[clampi(batch[i], BB - 1)], 1);
    if (i < BB * SS) stateBuf[i] = sa_in[i];
}

// ---------------- kHist: edges-per-dst histogram ----------------
__global__ __launch_bounds__(256) void kHist(const int* __restrict__ eidx,
                                             int* __restrict__ cnt) {
    for (int e = blockIdx.x * 256 + threadIdx.x; e < EE; e += gridDim.x * 256)
        atomicAdd(&cnt[clampi(eidx[EE + e], NN - 1)], 1);
}

// ---------------- 3-phase multi-block exclusive scan ----------------
__global__ __launch_bounds__(1024) void kScanA(const int* __restrict__ cnt,
                                               int* __restrict__ off,
                                               int* __restrict__ blkSum) {
    __shared__ int s[1024];
    int tid = threadIdx.x;
    int g = blockIdx.x * 1024 + tid;
    int v = (g < NN) ? cnt[g] : 0;
    s[tid] = v;
    __syncthreads();
#pragma unroll
    for (int o = 1; o < 1024; o <<= 1) {
        int x = (tid >= o) ? s[tid - o] : 0;
        __syncthreads();
        s[tid] += x;
        __syncthreads();
    }
    if (g < NN) off[g] = s[tid] - v;
    if (tid == 1023) blkSum[blockIdx.x] = s[1023];
}
__global__ void kScanB(int* __restrict__ blkSum, int nb) {
    if (threadIdx.x == 0) {
        int acc = 0;
        for (int i = 0; i < nb; i++) { int t = blkSum[i]; blkSum[i] = acc; acc += t; }
    }
}
__global__ __launch_bounds__(256) void kScanC(int* __restrict__ off,
                                              const int* __restrict__ blkSum) {
    int g = blockIdx.x * 256 + threadIdx.x;
    if (g < NN) off[g] += blkSum[g >> 10];
}

// ---------------- kScatter: pos[e] + sorted dst/src/C arrays ----------------
__global__ __launch_bounds__(256) void kScatter(const int* __restrict__ eidx,
                                                const float* __restrict__ ew,
                                                const int* __restrict__ off,
                                                int* __restrict__ cur,
                                                int* __restrict__ pos,
                                                int* __restrict__ ePerm,
                                                int* __restrict__ dstS,
                                                int* __restrict__ srcS,
                                                float* __restrict__ cS) {
    for (int e = blockIdx.x * 256 + threadIdx.x; e < EE; e += gridDim.x * 256) {
        int d = clampi(eidx[EE + e], NN - 1);
        int p = off[d] + atomicAdd(&cur[d], 1);
        pos[e] = p;
        ePerm[p] = e;
        dstS[p] = d;
        srcS[p] = clampi(eidx[e], NN - 1);
        float w = ew[e];
        cS[p] = 0.5f * (__cosf(w * 0.62831853072f) + 1.f);
    }
}

// ---------------- kPermEA: edge_attr -> sorted order, bf16, K zero-padded 50->64 ----------------
__global__ __launch_bounds__(256) void kPermEA(const float* __restrict__ ea,
                                               const int* __restrict__ pos,
                                               unsigned short* __restrict__ eaSb) {
    int idx = blockIdx.x * 256 + threadIdx.x;   // grid covers EE*4 exactly
    int e = idx >> 2, part = idx & 3;
    int p = pos[e];
    const float* src = ea + (size_t)e * 50 + part * 16;
    FragU f0, f1;
#pragma unroll
    for (int j = 0; j < 8; j++) f0.u[j] = (part * 16 + j < 50) ? f2bf(src[j]) : 0;
#pragma unroll
    for (int j = 0; j < 8; j++) f1.u[j] = (part * 16 + 8 + j < 50) ? f2bf(src[8 + j]) : 0;
    uint4* d = (uint4*)(eaSb + (size_t)p * 64 + part * 16);
    d[0] = f0.q; d[1] = f1.q;
}

// ---------------- kA: h2 = lin1([sa,h]) ; xf = conv_lin1(h2) ----------------
__global__ __launch_bounds__(256) void kA(const unsigned short* __restrict__ hb,   // [N,128] bf16
                                          const unsigned short* __restrict__ l1wb, // [128,130] bf16
                                          const float* __restrict__ lin1w,         // [128,130] fp32
                                          const float* __restrict__ lin1b,
                                          const unsigned short* __restrict__ c1wb, // [128,128] bf16
                                          const float* __restrict__ stateBuf,
                                          const int* __restrict__ batch,
                                          unsigned short* __restrict__ h2b,        // [N,128] bf16
                                          unsigned short* __restrict__ xfb) {      // [N,128] bf16
    __shared__ __align__(16) unsigned short P[64][136];
    int lane = threadIdx.x & 63;
    int wave = threadIdx.x >> 6;
    int m = lane & 15, q = lane >> 4;
    int rowBase = blockIdx.x * 64 + wave * 16;
    int arow = rowBase + m;
    int arowc = (arow < NN) ? arow : (NN - 1);

    floatx4 acc[8];
#pragma unroll
    for (int t = 0; t < 8; t++) acc[t] = (floatx4){0.f, 0.f, 0.f, 0.f};

#pragma unroll
    for (int k0 = 0; k0 < 128; k0 += 32) {
        bf16x8 a = load16(hb + (size_t)arowc * 128 + k0 + q * 8);
#pragma unroll
        for (int t = 0; t < 8; t++) {
            int n = t * 16 + m;
            bf16x8 b = loaddw(l1wb + (size_t)n * 130 + 2 + k0 + q * 8);
            acc[t] = __builtin_amdgcn_mfma_f32_16x16x32_bf16(a, b, acc[t], 0, 0, 0);
        }
    }

    int r0 = rowBase + q * 4;
    float s0[4], s1[4];
#pragma unroll
    for (int j = 0; j < 4; j++) {
        int r = r0 + j; int rc = (r < NN) ? r : (NN - 1);
        int g = clampi(batch[rc], BB - 1);
        s0[j] = stateBuf[g * 2 + 0];
        s1[j] = stateBuf[g * 2 + 1];
    }
#pragma unroll
    for (int t = 0; t < 8; t++) {
        int c = t * 16 + m;
        float w0 = lin1w[(size_t)c * 130 + 0];
        float w1 = lin1w[(size_t)c * 130 + 1];
        float bb = lin1b[c];
#pragma unroll
        for (int j = 0; j < 4; j++) {
            int r = r0 + j;
            unsigned short vb = f2bf(acc[t][j] + bb + s0[j] * w0 + s1[j] * w1);
            if (r < NN) h2b[(size_t)r * 128 + c] = vb;
            P[wave * 16 + q * 4 + j][c] = vb;
        }
    }
    __syncthreads();

    floatx4 acc2[8];
#pragma unroll
    for (int t = 0; t < 8; t++) acc2[t] = (floatx4){0.f, 0.f, 0.f, 0.f};
#pragma unroll
    for (int k0 = 0; k0 < 128; k0 += 32) {
        FragU fa; fa.q = *(const uint4*)&P[wave * 16 + m][k0 + q * 8];
#pragma unroll
        for (int t = 0; t < 8; t++) {
            int n = t * 16 + m;
            bf16x8 b = load16(c1wb + (size_t)n * 128 + k0 + q * 8);
            acc2[t] = __builtin_amdgcn_mfma_f32_16x16x32_bf16(fa.v, b, acc2[t], 0, 0, 0);
        }
    }
#pragma unroll
    for (int t = 0; t < 8; t++) {
        int c = t * 16 + m;
#pragma unroll
        for (int j = 0; j < 4; j++) {
            int r = r0 + j;
            if (r < NN) xfb[(size_t)r * 128 + c] = f2bf(acc2[t][j]);
        }
    }
}

// ---------------- kF: weight-resident fused edge kernel ----------------
// w1 in registers (per-lane frags), w2 in LDS (XOR-swizzled, loaded once/block).
// Each wave: 25 contiguous 16-edge sub-tiles, 1-deep eaSb prefetch, no main-loop barriers.
__global__ __launch_bounds__(256) void kF(const unsigned short* __restrict__ eaSb, // [E,64] bf16 sorted
                                          const unsigned short* __restrict__ w1pb, // [128,64] bf16 padded
                                          const float* __restrict__ b1,
                                          const unsigned short* __restrict__ w2b,  // [128,128] bf16
                                          const float* __restrict__ b2,
                                          const int* __restrict__ dstS,
                                          const int* __restrict__ srcS,
                                          const float* __restrict__ cS,
                                          const unsigned short* __restrict__ xfb,
                                          float* __restrict__ agg) {
    __shared__ __align__(16) char w2L[32768];               // [128][128] bf16, XOR-swizzled rows
    __shared__ __align__(16) unsigned short P[4][16][136];  // per-wave hidden, then xf rows
    __shared__ float accW[4][SLOTW][132];                   // per-wave dst accumulators
    __shared__ int slotDst[4][16];

    int tid = threadIdx.x;
    int lane = tid & 63;
    int w = tid >> 6;
    int m = lane & 15, q = lane >> 4;

    // --- cooperative w2 -> LDS (swizzled: byte ^= (n&7)<<4 within 256B row) ---
    // 128 rows x 16 chunks of 16B = full 32 KB (fix: was 8 chunks -> half row uninitialized)
    for (int idx = tid; idx < 128 * 16; idx += 256) {
        int n = idx >> 4, ch = idx & 15;
        uint4 v = *(const uint4*)(w2b + (size_t)n * 128 + ch * 8);
        int bo = n * 256 + ((ch * 16) ^ ((n & 7) << 4));
        *(uint4*)(w2L + bo) = v;
    }

    // --- w1 frags + biases to registers (once per wave) ---
    bf16x8 w1lo[8], w1hi[8];
    float b1v[8], b2v[8];
#pragma unroll
    for (int t = 0; t < 8; t++) {
        int n = t * 16 + m;
        w1lo[t] = load16(w1pb + (size_t)n * 64 + q * 8);
        w1hi[t] = load16(w1pb + (size_t)n * 64 + 32 + q * 8);
        b1v[t] = b1[n];
        b2v[t] = b2[n];
    }
    __syncthreads();   // w2L ready (only barrier in the kernel)

    int base = (blockIdx.x * 4 + w) * (NTPW * 16);
    int gr = lane >> 2, gc = lane & 3;

    // prologue: first sub-tile's eaSb
    bf16x8 a0 = load16(eaSb + (size_t)(base + m) * 64 + q * 8);
    bf16x8 a1 = load16(eaSb + (size_t)(base + m) * 64 + 32 + q * 8);

    for (int it = 0; it < NTPW; ++it, base += 16) {
        // prefetch next sub-tile's eaSb
        bf16x8 a0n = a0, a1n = a1;
        if (it < NTPW - 1) {
            a0n = load16(eaSb + (size_t)(base + 16 + m) * 64 + q * 8);
            a1n = load16(eaSb + (size_t)(base + 16 + m) * 64 + 32 + q * 8);
        }
        // current meta (L2-hot sequential)
        int d_r = dstS[base + m];
        int gsrc = srcS[base + gr];
        float Cj[4];
#pragma unroll
        for (int j = 0; j < 4; j++) Cj[j] = cS[base + q * 4 + j];

        // --- GEMM1: registers only ---
        floatx4 acc[8];
#pragma unroll
        for (int t = 0; t < 8; t++) {
            floatx4 z = (floatx4){0.f, 0.f, 0.f, 0.f};
            z = __builtin_amdgcn_mfma_f32_16x16x32_bf16(a0, w1lo[t], z, 0, 0, 0);
            acc[t] = __builtin_amdgcn_mfma_f32_16x16x32_bf16(a1, w1hi[t], z, 0, 0, 0);
        }

        // --- slot/run computation, register-only ---
        int dp = __shfl(d_r, (lane - 1) & 63);
        bool flag = (m == 0) || (d_r != dp);
        unsigned long long bm = __ballot(flag ? 1 : 0);
        unsigned int bmlow = (unsigned int)(bm & 0xFFFFull);
        int D = __popc(bmlow);
        int Dc = (D < SLOTW) ? D : SLOTW;
        {
            int slot_m = __popc(bmlow & ((2u << m) - 1u)) - 1;
            if (lane < 16 && flag) slotDst[w][slot_m] = d_r;
        }
        int sl[4];
#pragma unroll
        for (int j = 0; j < 4; j++)
            sl[j] = __popc(bmlow & ((2u << (q * 4 + j)) - 1u)) - 1;

        // --- ssp + P write ---
#pragma unroll
        for (int t = 0; t < 8; t++) {
            int c = t * 16 + m;
#pragma unroll
            for (int j = 0; j < 4; j++)
                P[w][q * 4 + j][c] = f2bf(sspf(acc[t][j] + b1v[t]));
        }

        // --- issue xf gathers (land under GEMM2) ---
        const uint4* gs = (const uint4*)&xfb[(size_t)gsrc * 128 + gc * 32];
        uint4 x0 = gs[0], x1 = gs[1], x2 = gs[2], x3 = gs[3];

        // zero live accW rows
        {
            float* fl = &accW[w][0][0];
            for (int i = lane; i < Dc * 132; i += 64) fl[i] = 0.f;
        }

        // --- GEMM2: P (LDS) x w2L (LDS, swizzled) ---
        floatx4 acc2[8];
#pragma unroll
        for (int t = 0; t < 8; t++) acc2[t] = (floatx4){0.f, 0.f, 0.f, 0.f};
#pragma unroll
        for (int k0 = 0; k0 < 128; k0 += 32) {
            FragU fa; fa.q = *(const uint4*)&P[w][m][k0 + q * 8];
#pragma unroll
            for (int t = 0; t < 8; t++) {
                int n = t * 16 + m;
                int bo = n * 256 + ((((k0 + q * 8) * 2)) ^ ((n & 7) << 4));
                bf16x8 b = load16((const unsigned short*)(w2L + bo));
                acc2[t] = __builtin_amdgcn_mfma_f32_16x16x32_bf16(fa.v, b, acc2[t], 0, 0, 0);
            }
        }

        // park staged xf rows in P (after this wave's GEMM2 reads)
        {
            uint4* dptr = (uint4*)&P[w][gr][gc * 32];
            dptr[0] = x0; dptr[1] = x1; dptr[2] = x2; dptr[3] = x3;
        }

        // --- epilogue: msg = (eh + b2) * C * xf[src], run-combine by dst slot ---
#pragma unroll
        for (int t = 0; t < 8; t++) {
            int c = t * 16 + m;
            float bb = b2v[t];
            float v4[4];
#pragma unroll
            for (int j = 0; j < 4; j++)
                v4[j] = (acc2[t][j] + bb) * Cj[j] * bf2f(P[w][q * 4 + j][c]);
            float run = v4[0];
#pragma unroll
            for (int j = 1; j < 4; j++) {
                if (sl[j] == sl[j - 1]) run += v4[j];
                else {
                    int s = sl[j - 1];
                    if (s < SLOTW) atomicAdd(&accW[w][s][c], run);
                    else unsafeAtomicAdd(&agg[(size_t)slotDst[w][s] * 128 + c], run);
                    run = v4[j];
                }
            }
            {
                int s = sl[3];
                if (s < SLOTW) atomicAdd(&accW[w][s][c], run);
                else unsafeAtomicAdd(&agg[(size_t)slotDst[w][s] * 128 + c], run);
            }
        }

        // --- flush: interior slots fully owned -> plain store; boundary -> atomic ---
        for (int i = lane; i < Dc * 128; i += 64) {
            int s = i >> 7, cc = i & 127;
            float v = accW[w][s][cc];
            size_t o = (size_t)slotDst[w][s] * 128 + cc;
            if (s > 0 && s < D - 1) agg[o] = v;
            else unsafeAtomicAdd(&agg[o], v);
        }

        a0 = a0n; a1 = a1n;
    }
}

// ---------------- kE2 (fallback when workspace too small for eaSb) ----------------
__global__ __launch_bounds__(256) void kE2(const float* __restrict__ ea,
                                           const unsigned short* __restrict__ w1b,
                                           const float* __restrict__ b1,
                                           const unsigned short* __restrict__ w2b,
                                           const float* __restrict__ b2,
                                           const int* __restrict__ ePerm,
                                           const int* __restrict__ dstS,
                                           const int* __restrict__ srcS,
                                           const float* __restrict__ cS,
                                           const unsigned short* __restrict__ xfb,
                                           float* __restrict__ agg) {
    __shared__ __align__(16) unsigned short P[64][136];
    __shared__ float accS[64][132];
    __shared__ int sSlot[64];
    __shared__ int sSlotDst[64];
    __shared__ int sD;

    int tid = threadIdx.x;
    int lane = tid & 63;
    int wave = tid >> 6;
    int m = lane & 15, q = lane >> 4;
    int base = blockIdx.x * 64;

    float* accFlat = &accS[0][0];
    for (int i = tid; i < 64 * 132; i += 256) accFlat[i] = 0.f;

    if (tid < 64) {
        int i = tid;
        int di = dstS[base + i];
        bool flag = (i == 0) || (di != dstS[base + i - 1]);
        unsigned long long bm = __ballot(flag ? 1 : 0);
        unsigned long long low = (i == 63) ? ~0ull : ((1ull << (i + 1)) - 1ull);
        int slot = (int)__popcll(bm & low) - 1;
        sSlot[i] = slot;
        if (flag) sSlotDst[slot] = di;
        if (i == 63) sD = slot + 1;
    }

    int eRow = ePerm[base + wave * 16 + m];

    floatx4 acc[8];
#pragma unroll
    for (int t = 0; t < 8; t++) acc[t] = (floatx4){0.f, 0.f, 0.f, 0.f};
    {
        bf16x8 a = f8frag(ea + (size_t)eRow * 50 + q * 8);
#pragma unroll
        for (int t = 0; t < 8; t++) {
            int n = t * 16 + m;
            bf16x8 b = loaddw(w1b + (size_t)n * 50 + q * 8);
            acc[t] = __builtin_amdgcn_mfma_f32_16x16x32_bf16(a, b, acc[t], 0, 0, 0);
        }
    }
    {
        int kbase = 32 + q * 8;
        FragU fa;
        const float* pa = ea + (size_t)eRow * 50 + kbase;
#pragma unroll
        for (int j = 0; j < 8; j++) fa.u[j] = (kbase + j < 50) ? f2bf(pa[j]) : 0;
#pragma unroll
        for (int t = 0; t < 8; t++) {
            int n = t * 16 + m;
            FragU fb;
            const unsigned int* pb = (const unsigned int*)(w1b + (size_t)n * 50 + kbase);
#pragma unroll
            for (int t2 = 0; t2 < 4; t2++) fb.d[t2] = (kbase + 2 * t2 < 50) ? pb[t2] : 0u;
            acc[t] = __builtin_amdgcn_mfma_f32_16x16x32_bf16(fa.v, fb.v, acc[t], 0, 0, 0);
        }
    }
#pragma unroll
    for (int t = 0; t < 8; t++) {
        int c = t * 16 + m;
        float bb = b1[c];
#pragma unroll
        for (int j = 0; j < 4; j++)
            P[wave * 16 + q * 4 + j][c] = f2bf(sspf(acc[t][j] + bb));
    }
    __syncthreads();

    floatx4 acc2[8];
#pragma unroll
    for (int t = 0; t < 8; t++) acc2[t] = (floatx4){0.f, 0.f, 0.f, 0.f};
#pragma unroll
    for (int k0 = 0; k0 < 128; k0 += 32) {
        FragU fa; fa.q = *(const uint4*)&P[wave * 16 + m][k0 + q * 8];
#pragma unroll
        for (int t = 0; t < 8; t++) {
            int n = t * 16 + m;
            bf16x8 b = load16(w2b + (size_t)n * 128 + k0 + q * 8);
            acc2[t] = __builtin_amdgcn_mfma_f32_16x16x32_bf16(fa.v, b, acc2[t], 0, 0, 0);
        }
    }

    int sl[4], srcj[4]; float Cj[4];
#pragma unroll
    for (int j = 0; j < 4; j++) {
        int r = wave * 16 + q * 4 + j;
        int g = base + r;
        sl[j] = sSlot[r];
        Cj[j] = cS[g];
        srcj[j] = srcS[g];
    }
#pragma unroll
    for (int t = 0; t < 8; t++) {
        int c = t * 16 + m;
        float bb = b2[c];
        float v4[4];
#pragma unroll
        for (int j = 0; j < 4; j++)
            v4[j] = (acc2[t][j] + bb) * Cj[j] * bf2f(xfb[(size_t)srcj[j] * 128 + c]);
        float run = v4[0];
#pragma unroll
        for (int j = 1; j < 4; j++) {
            if (sl[j] == sl[j - 1]) run += v4[j];
            else { atomicAdd(&accS[sl[j - 1]][c], run); run = v4[j]; }
        }
        atomicAdd(&accS[sl[3]][c], run);
    }
    __syncthreads();

    int D = sD;
    for (int idx = tid; idx < D * 128; idx += 256) {
        int s = idx >> 7, c = idx & 127;
        unsafeAtomicAdd(&agg[(size_t)sSlotDst[s] * 128 + c], accS[s][c]);
    }
}

// ---------------- kC: xc = conv_lin2(agg); h = h2 + ssp(xc); pooling ----------------
__global__ __launch_bounds__(256) void kC(const float* __restrict__ agg,
                                          const unsigned short* __restrict__ wb,
                                          const float* __restrict__ b,
                                          const unsigned short* __restrict__ h2b,
                                          unsigned short* __restrict__ hnb,
                                          const int* __restrict__ batch,
                                          float* __restrict__ pool,
                                          int doPool) {
    int lane = threadIdx.x & 63;
    int wave = threadIdx.x >> 6;
    int m = lane & 15, q = lane >> 4;
    int rowBase = blockIdx.x * 64 + wave * 16;
    int arow = rowBase + m;
    int arowc = (arow < NN) ? arow : (NN - 1);

    floatx4 acc[8];
#pragma unroll
    for (int t = 0; t < 8; t++) acc[t] = (floatx4){0.f, 0.f, 0.f, 0.f};

#pragma unroll
    for (int k0 = 0; k0 < 128; k0 += 32) {
        bf16x8 fa = f8frag(agg + (size_t)arowc * 128 + k0 + q * 8);
#pragma unroll
        for (int t = 0; t < 8; t++) {
            int n = t * 16 + m;
            bf16x8 bfr = load16(wb + (size_t)n * 128 + k0 + q * 8);
            acc[t] = __builtin_amdgcn_mfma_f32_16x16x32_bf16(fa, bfr, acc[t], 0, 0, 0);
        }
    }

    int r0 = rowBase + q * 4;
    float vsum[4] = {0.f, 0.f, 0.f, 0.f};
#pragma unroll
    for (int t = 0; t < 8; t++) {
        int c = t * 16 + m;
        float bb = b[c];
#pragma unroll
        for (int j = 0; j < 4; j++) {
            int r = r0 + j; int rc = (r < NN) ? r : (NN - 1);
            float v = bf2f(h2b[(size_t)rc * 128 + c]) + sspf(acc[t][j] + bb);
            if (r < NN) {
                hnb[(size_t)r * 128 + c] = f2bf(v);
                vsum[j] += v;
            }
        }
    }
    if (doPool) {
#pragma unroll
        for (int j = 0; j < 4; j++) {
            float v = vsum[j];
#pragma unroll
            for (int off = 1; off < 16; off <<= 1) v += __shfl_xor(v, off, 16);
            int r = r0 + j;
            if (m == 0 && r < NN) unsafeAtomicAdd(&pool[clampi(batch[r], BB - 1)], v);
        }
    }
}

// ---------------- kS ----------------
__global__ __launch_bounds__(256) void kS(const float* __restrict__ pool,
                                          const int* __restrict__ counts,
                                          float* __restrict__ stateBuf) {
    int b = threadIdx.x;
    if (b < BB) {
        float c = (float)counts[b];
        c = (c < 1.f) ? 1.f : c;
        float v = pool[b] / c;
        stateBuf[b * 2 + 0] = v;
        stateBuf[b * 2 + 1] = v;
    }
}

// ---------------- kOut ----------------
__global__ __launch_bounds__(256) void kOut(const unsigned short* __restrict__ hnb,
                                            const unsigned short* __restrict__ owb,
                                            const float* __restrict__ ob,
                                            float* __restrict__ out) {
    int lane = threadIdx.x & 63;
    int wave = threadIdx.x >> 6;
    int m = lane & 15, q = lane >> 4;
    int rowBase = blockIdx.x * 64 + wave * 16;
    int arow = rowBase + m;
    int arowc = (arow < NN) ? arow : (NN - 1);

    floatx4 acc[8];
#pragma unroll
    for (int t = 0; t < 8; t++) acc[t] = (floatx4){0.f, 0.f, 0.f, 0.f};
#pragma unroll
    for (int k0 = 0; k0 < 128; k0 += 32) {
        bf16x8 a = load16(hnb + (size_t)arowc * 128 + k0 + q * 8);
#pragma unroll
        for (int t = 0; t < 8; t++) {
            int n = t * 16 + m;
            bf16x8 bfr = load16(owb + (size_t)n * 128 + k0 + q * 8);
            acc[t] = __builtin_amdgcn_mfma_f32_16x16x32_bf16(a, bfr, acc[t], 0, 0, 0);
        }
    }
    int r0 = rowBase + q * 4;
#pragma unroll
    for (int t = 0; t < 8; t++) {
        int c = t * 16 + m;
        float bb = ob[c];
#pragma unroll
        for (int j = 0; j < 4; j++) {
            int r = r0 + j;
            if (r < NN) out[(size_t)r * 128 + c] = acc[t][j] + bb;
        }
    }
}

extern "C" void kernel_launch(void* const* d_in, const int* in_sizes, int n_in,
                              void* d_out, int out_size, void* d_ws, size_t ws_size,
                              hipStream_t stream) {
    const float* h     = (const float*)d_in[0];
    const float* ew    = (const float*)d_in[1];
    const float* ea    = (const float*)d_in[2];
    const float* sa    = (const float*)d_in[3];
    const float* lin1w = (const float*)d_in[4];
    const float* lin1b = (const float*)d_in[5];
    const float* mw1   = (const float*)d_in[6];
    const float* mb1   = (const float*)d_in[7];
    const float* mw2   = (const float*)d_in[8];
    const float* mb2   = (const float*)d_in[9];
    const float* c1w   = (const float*)d_in[10];
    const float* c2w   = (const float*)d_in[11];
    const float* c2b   = (const float*)d_in[12];
    const float* outw  = (const float*)d_in[13];
    const float* outb  = (const float*)d_in[14];
    const int* eidx    = (const int*)d_in[15];
    const int* batch   = (const int*)d_in[16];
    float* out = (float*)d_out;

    char* ws = (char*)d_ws;
    unsigned short* hnb   = (unsigned short*)(ws);              // 12.8 MB
    unsigned short* h2b   = (unsigned short*)(ws + 12800000);   // 12.8 MB
    unsigned short* xfb   = (unsigned short*)(ws + 25600000);   // 12.8 MB
    float*          agg   = (float*)(ws + 38400000);            // 25.6 MB
    int*            pos   = (int*)(ws + 64000000);              // 3.2 MB
    int*            ePerm = (int*)(ws + 67200000);              // 3.2 MB (fallback only)
    int*            dstS  = (int*)(ws + 70400000);              // 3.2 MB
    int*            srcS  = (int*)(ws + 73600000);              // 3.2 MB
    float*          cS    = (float*)(ws + 76800000);            // 3.2 MB
    int*            cnt   = (int*)(ws + 80000000);              // 200 KB
    int*            off   = (int*)(ws + 80200000);              // 200 KB
    int*            cur   = (int*)(ws + 80400000);              // 200 KB
    int*            blkSum= (int*)(ws + 80600000);              // 256 B
    unsigned short* wb    = (unsigned short*)(ws + 80600512);   // 354,304 B (177152 ushorts)
    float*          pool  = (float*)(ws + 80954816);
    int*            counts= (int*)(ws + 80955840);
    float*          stateBuf = (float*)(ws + 80956864);
    const size_t EAOFF = 80958912;                              // 16B aligned
    unsigned short* eaSb = (unsigned short*)(ws + EAOFF);       // 102.4 MB

    const size_t need = EAOFF + (size_t)EE * 64 * 2;
    const int useF = (ws_size >= need) ? 1 : 0;

    // bf16 weight banks
    unsigned short* mw1b = wb;            // [2][128][50]   (fallback kE2)
    unsigned short* mw2b = wb + 12800;    // [2][128][128]
    unsigned short* c1wb = wb + 45568;    // [2][128][128]
    unsigned short* c2wb = wb + 78336;    // [2][128][128]
    unsigned short* l1wb = wb + 111104;   // [2][128][130]
    unsigned short* owb  = wb + 144384;   // [128][128]
    unsigned short* w1pb = wb + 160768;   // [2][128][64]  zero-padded mlp_w1

    hipMemsetAsync(cnt, 0, NN * 4, stream);
    hipMemsetAsync(cur, 0, NN * 4, stream);
    hipMemsetAsync(counts, 0, BB * 4, stream);
    hipMemsetAsync(pool, 0, BB * 4, stream);

    kPrep<<<(NN + 255) / 256, 256, 0, stream>>>(batch, counts, sa, stateBuf);
    kHist<<<1024, 256, 0, stream>>>(eidx, cnt);
    kScanA<<<(NN + 1023) / 1024, 1024, 0, stream>>>(cnt, off, blkSum);
    kScanB<<<1, 64, 0, stream>>>(blkSum, (NN + 1023) / 1024);
    kScanC<<<(NN + 255) / 256, 256, 0, stream>>>(off, blkSum);
    kScatter<<<1024, 256, 0, stream>>>(eidx, ew, off, cur, pos, ePerm, dstS, srcS, cS);

    kConvW<<<177152 / 256, 256, 0, stream>>>(mw1, mw2, c1w, c2w, lin1w, outw, wb);
    kConv<<<4096, 256, 0, stream>>>(h, hnb, NN * 128);
    if (useF) {
        kPermEA<<<(EE * 4) / 256, 256, 0, stream>>>(ea, pos, eaSb);   // once: ea constant over layers
    }

    const int gridN = (NN + 63) / 64;   // 782

    for (int i = 0; i < 2; i++) {
        hipMemsetAsync(agg, 0, (size_t)NN * 128 * 4, stream);
        kA<<<gridN, 256, 0, stream>>>(hnb,
                                      l1wb + (size_t)i * 128 * 130,
                                      lin1w + (size_t)i * 128 * 130,
                                      lin1b + (size_t)i * 128,
                                      c1wb + (size_t)i * 128 * 128,
                                      stateBuf, batch, h2b, xfb);
        if (useF) {
            kF<<<KFBLK, 256, 0, stream>>>(eaSb,
                                          w1pb + (size_t)i * 128 * 64,
                                          mb1 + (size_t)i * 128,
                                          mw2b + (size_t)i * 128 * 128,
                                          mb2 + (size_t)i * 128,
                                          dstS, srcS, cS, xfb, agg);
        } else {
            kE2<<<EE / 64, 256, 0, stream>>>(ea,
                                             mw1b + (size_t)i * 128 * 50,
                                             mb1 + (size_t)i * 128,
                                             mw2b + (size_t)i * 128 * 128,
                                             mb2 + (size_t)i * 128,
                                             ePerm, dstS, srcS, cS, xfb, agg);
        }
        kC<<<gridN, 256, 0, stream>>>(agg,
                                      c2wb + (size_t)i * 128 * 128,
                                      c2b + (size_t)i * 128,
                                      h2b, hnb, batch, pool, (i == 0) ? 1 : 0);
        if (i == 0) kS<<<1, 256, 0, stream>>>(pool, counts, stateBuf);
    }
    kOut<<<gridN, 256, 0, stream>>>(hnb, owb, outb, out);
}

// Round 7
// 1274.390 us; speedup vs baseline: 1.2206x; 1.0114x over previous
//
#include <hip/hip_runtime.h>

#define NN 50000
#define EE 800000
#define HH 128
#define GG 50
#define FF 128
#define SS 2
#define BB 256
#define KFBLK 500      // kF grid: 500 blocks x 4 waves x 25 subtiles x 16 edges = 800000
#define NTPW 25        // sub-tiles per wave

typedef short bf16x8 __attribute__((ext_vector_type(8)));
typedef float floatx4 __attribute__((ext_vector_type(4)));

union FragU { bf16x8 v; unsigned short u[8]; unsigned int d[4]; uint4 q; };

__device__ __forceinline__ float bf2f(unsigned short u) {
    union { unsigned int i; float f; } c; c.i = ((unsigned int)u) << 16; return c.f;
}
__device__ __forceinline__ unsigned short f2bf(float f) {
    union { float f; unsigned int i; } c; c.f = f;
    unsigned int i = c.i;
    unsigned int r = (i + 0x7fffu + ((i >> 16) & 1u)) >> 16;
    return (unsigned short)r;
}
__device__ __forceinline__ float sspf(float x) {
    float l = __logf(1.f + __expf(x));
    l = (x > 20.f) ? x : l;
    return l - 0.69314718056f;
}
__device__ __forceinline__ bf16x8 f8frag(const float* p) {       // fp32 -> bf16 frag
    FragU f;
#pragma unroll
    for (int j = 0; j < 8; j++) f.u[j] = f2bf(p[j]);
    return f.v;
}
__device__ __forceinline__ bf16x8 load16(const unsigned short* p) { // 16B-aligned bf16
    FragU f; f.q = *(const uint4*)p; return f.v;
}
__device__ __forceinline__ bf16x8 loaddw(const unsigned short* p) { // 4B-aligned bf16
    FragU f; const unsigned int* pp = (const unsigned int*)p;
#pragma unroll
    for (int t = 0; t < 4; t++) f.d[t] = pp[t];
    return f.v;
}
__device__ __forceinline__ int clampi(int v, int hi) {
    v = (v < 0) ? 0 : v;
    return (v > hi) ? hi : v;
}

// ---------------- kConv: fp32 -> bf16 bulk convert ----------------
__global__ __launch_bounds__(256) void kConv(const float* __restrict__ s,
                                             unsigned short* __restrict__ d, int n) {
    for (int i = blockIdx.x * 256 + threadIdx.x; i < n; i += gridDim.x * 256)
        d[i] = f2bf(s[i]);
}

// ---------------- kConvW: all weight arrays -> bf16 bank (+ K=64 zero-padded mlp_w1) ----------------
__global__ __launch_bounds__(256) void kConvW(const float* __restrict__ a0,  // mw1 12800
                                              const float* __restrict__ a1,  // mw2 32768
                                              const float* __restrict__ a2,  // c1w 32768
                                              const float* __restrict__ a3,  // c2w 32768
                                              const float* __restrict__ a4,  // lin1w 33280
                                              const float* __restrict__ a5,  // outw 16384
                                              unsigned short* __restrict__ d) {
    int i = blockIdx.x * 256 + threadIdx.x;   // grid covers 177152 exactly
    float v;
    if (i < 12800)        v = a0[i];
    else if (i < 45568)   v = a1[i - 12800];
    else if (i < 78336)   v = a2[i - 45568];
    else if (i < 111104)  v = a3[i - 78336];
    else if (i < 144384)  v = a4[i - 111104];
    else if (i < 160768)  v = a5[i - 144384];
    else {
        // padded mlp_w1: [2][128][64], zero beyond col 50
        int j = i - 160768;           // 0..16383
        int k = j & 63;
        int nl = j >> 6;              // layer*128 + n
        v = (k < 50) ? a0[nl * 50 + k] : 0.f;
    }
    d[i] = f2bf(v);
}

// ---------------- kPrep: batch histogram + state init ----------------
__global__ __launch_bounds__(256) void kPrep(const int* __restrict__ batch,
                                             int* __restrict__ counts,
                                             const float* __restrict__ sa_in,
                                             float* __restrict__ stateBuf) {
    int i = blockIdx.x * 256 + threadIdx.x;
    if (i < NN) atomicAdd(&counts[clampi(batch[i], BB - 1)], 1);
    if (i < BB * SS) stateBuf[i] = sa_in[i];
}

// ---------------- kHist: edges-per-dst histogram ----------------
__global__ __launch_bounds__(256) void kHist(const int* __restrict__ eidx,
                                             int* __restrict__ cnt) {
    for (int e = blockIdx.x * 256 + threadIdx.x; e < EE; e += gridDim.x * 256)
        atomicAdd(&cnt[clampi(eidx[EE + e], NN - 1)], 1);
}

// ---------------- 3-phase multi-block exclusive scan ----------------
__global__ __launch_bounds__(1024) void kScanA(const int* __restrict__ cnt,
                                               int* __restrict__ off,
                                               int* __restrict__ blkSum) {
    __shared__ int s[1024];
    int tid = threadIdx.x;
    int g = blockIdx.x * 1024 + tid;
    int v = (g < NN) ? cnt[g] : 0;
    s[tid] = v;
    __syncthreads();
#pragma unroll
    for (int o = 1; o < 1024; o <<= 1) {
        int x = (tid >= o) ? s[tid - o] : 0;
        __syncthreads();
        s[tid] += x;
        __syncthreads();
    }
    if (g < NN) off[g] = s[tid] - v;
    if (tid == 1023) blkSum[blockIdx.x] = s[1023];
}
__global__ void kScanB(int* __restrict__ blkSum, int nb) {
    if (threadIdx.x == 0) {
        int acc = 0;
        for (int i = 0; i < nb; i++) { int t = blkSum[i]; blkSum[i] = acc; acc += t; }
    }
}
__global__ __launch_bounds__(256) void kScanC(int* __restrict__ off,
                                              const int* __restrict__ blkSum) {
    int g = blockIdx.x * 256 + threadIdx.x;
    if (g < NN) off[g] += blkSum[g >> 10];
}

// ---------------- kScatter: pos[e] + sorted dst/src/C arrays ----------------
__global__ __launch_bounds__(256) void kScatter(const int* __restrict__ eidx,
                                                const float* __restrict__ ew,
                                                const int* __restrict__ off,
                                                int* __restrict__ cur,
                                                int* __restrict__ pos,
                                                int* __restrict__ ePerm,
                                                int* __restrict__ dstS,
                                                int* __restrict__ srcS,
                                                float* __restrict__ cS) {
    for (int e = blockIdx.x * 256 + threadIdx.x; e < EE; e += gridDim.x * 256) {
        int d = clampi(eidx[EE + e], NN - 1);
        int p = off[d] + atomicAdd(&cur[d], 1);
        pos[e] = p;
        ePerm[p] = e;
        dstS[p] = d;
        srcS[p] = clampi(eidx[e], NN - 1);
        float w = ew[e];
        cS[p] = 0.5f * (__cosf(w * 0.62831853072f) + 1.f);
    }
}

// ---------------- kPermEA: edge_attr -> sorted order, bf16, K zero-padded 50->64 ----------------
__global__ __launch_bounds__(256) void kPermEA(const float* __restrict__ ea,
                                               const int* __restrict__ pos,
                                               unsigned short* __restrict__ eaSb) {
    int idx = blockIdx.x * 256 + threadIdx.x;   // grid covers EE*4 exactly
    int e = idx >> 2, part = idx & 3;
    int p = pos[e];
    const float* src = ea + (size_t)e * 50 + part * 16;
    FragU f0, f1;
#pragma unroll
    for (int j = 0; j < 8; j++) f0.u[j] = (part * 16 + j < 50) ? f2bf(src[j]) : 0;
#pragma unroll
    for (int j = 0; j < 8; j++) f1.u[j] = (part * 16 + 8 + j < 50) ? f2bf(src[8 + j]) : 0;
    uint4* d = (uint4*)(eaSb + (size_t)p * 64 + part * 16);
    d[0] = f0.q; d[1] = f1.q;
}

// ---------------- kA: h2 = lin1([sa,h]) ; xf = conv_lin1(h2) ----------------
__global__ __launch_bounds__(256) void kA(const unsigned short* __restrict__ hb,   // [N,128] bf16
                                          const unsigned short* __restrict__ l1wb, // [128,130] bf16
                                          const float* __restrict__ lin1w,         // [128,130] fp32
                                          const float* __restrict__ lin1b,
                                          const unsigned short* __restrict__ c1wb, // [128,128] bf16
                                          const float* __restrict__ stateBuf,
                                          const int* __restrict__ batch,
                                          unsigned short* __restrict__ h2b,        // [N,128] bf16
                                          unsigned short* __restrict__ xfb) {      // [N,128] bf16
    __shared__ __align__(16) unsigned short P[64][136];
    int lane = threadIdx.x & 63;
    int wave = threadIdx.x >> 6;
    int m = lane & 15, q = lane >> 4;
    int rowBase = blockIdx.x * 64 + wave * 16;
    int arow = rowBase + m;
    int arowc = (arow < NN) ? arow : (NN - 1);

    floatx4 acc[8];
#pragma unroll
    for (int t = 0; t < 8; t++) acc[t] = (floatx4){0.f, 0.f, 0.f, 0.f};

#pragma unroll
    for (int k0 = 0; k0 < 128; k0 += 32) {
        bf16x8 a = load16(hb + (size_t)arowc * 128 + k0 + q * 8);
#pragma unroll
        for (int t = 0; t < 8; t++) {
            int n = t * 16 + m;
            bf16x8 b = loaddw(l1wb + (size_t)n * 130 + 2 + k0 + q * 8);
            acc[t] = __builtin_amdgcn_mfma_f32_16x16x32_bf16(a, b, acc[t], 0, 0, 0);
        }
    }

    int r0 = rowBase + q * 4;
    float s0[4], s1[4];
#pragma unroll
    for (int j = 0; j < 4; j++) {
        int r = r0 + j; int rc = (r < NN) ? r : (NN - 1);
        int g = clampi(batch[rc], BB - 1);
        s0[j] = stateBuf[g * 2 + 0];
        s1[j] = stateBuf[g * 2 + 1];
    }
#pragma unroll
    for (int t = 0; t < 8; t++) {
        int c = t * 16 + m;
        float w0 = lin1w[(size_t)c * 130 + 0];
        float w1 = lin1w[(size_t)c * 130 + 1];
        float bb = lin1b[c];
#pragma unroll
        for (int j = 0; j < 4; j++) {
            int r = r0 + j;
            unsigned short vb = f2bf(acc[t][j] + bb + s0[j] * w0 + s1[j] * w1);
            if (r < NN) h2b[(size_t)r * 128 + c] = vb;
            P[wave * 16 + q * 4 + j][c] = vb;
        }
    }
    __syncthreads();

    floatx4 acc2[8];
#pragma unroll
    for (int t = 0; t < 8; t++) acc2[t] = (floatx4){0.f, 0.f, 0.f, 0.f};
#pragma unroll
    for (int k0 = 0; k0 < 128; k0 += 32) {
        FragU fa; fa.q = *(const uint4*)&P[wave * 16 + m][k0 + q * 8];
#pragma unroll
        for (int t = 0; t < 8; t++) {
            int n = t * 16 + m;
            bf16x8 b = load16(c1wb + (size_t)n * 128 + k0 + q * 8);
            acc2[t] = __builtin_amdgcn_mfma_f32_16x16x32_bf16(fa.v, b, acc2[t], 0, 0, 0);
        }
    }
#pragma unroll
    for (int t = 0; t < 8; t++) {
        int c = t * 16 + m;
#pragma unroll
        for (int j = 0; j < 4; j++) {
            int r = r0 + j;
            if (r < NN) xfb[(size_t)r * 128 + c] = f2bf(acc2[t][j]);
        }
    }
}

// ---------------- kF: weight-resident fused edge kernel, register run-carry ----------------
// w1 in registers, w2 in LDS (XOR-swizzled). No accW: run-combine in registers with
// cross-subtile carry; flush to agg via coalesced global atomics only on dst change.
// LDS 50.2 KB -> 3 blocks/CU. No LDS atomics (kills the 8.8M bank conflicts).
__global__ __launch_bounds__(256) void kF(const unsigned short* __restrict__ eaSb, // [E,64] bf16 sorted
                                          const unsigned short* __restrict__ w1pb, // [128,64] bf16 padded
                                          const float* __restrict__ b1,
                                          const unsigned short* __restrict__ w2b,  // [128,128] bf16
                                          const float* __restrict__ b2,
                                          const int* __restrict__ dstS,
                                          const int* __restrict__ srcS,
                                          const float* __restrict__ cS,
                                          const unsigned short* __restrict__ xfb,
                                          float* __restrict__ agg) {
    __shared__ __align__(16) char w2L[32768];               // [128][128] bf16, XOR-swizzled rows
    __shared__ __align__(16) unsigned short P[4][16][136];  // per-wave hidden, then xf rows

    int tid = threadIdx.x;
    int lane = tid & 63;
    int w = tid >> 6;
    int m = lane & 15, q = lane >> 4;

    // --- cooperative w2 -> LDS (full 32 KB; swizzle: byte ^= (n&7)<<4 within 256B row) ---
    for (int idx = tid; idx < 128 * 16; idx += 256) {
        int n = idx >> 4, ch = idx & 15;
        uint4 v = *(const uint4*)(w2b + (size_t)n * 128 + ch * 8);
        int bo = n * 256 + ((ch * 16) ^ ((n & 7) << 4));
        *(uint4*)(w2L + bo) = v;
    }

    // --- w1 frags + biases to registers (once per wave) ---
    bf16x8 w1lo[8], w1hi[8];
    float b1v[8], b2v[8];
#pragma unroll
    for (int t = 0; t < 8; t++) {
        int n = t * 16 + m;
        w1lo[t] = load16(w1pb + (size_t)n * 64 + q * 8);
        w1hi[t] = load16(w1pb + (size_t)n * 64 + 32 + q * 8);
        b1v[t] = b1[n];
        b2v[t] = b2[n];
    }
    __syncthreads();   // w2L ready (only barrier in the kernel)

    int base = (blockIdx.x * 4 + w) * (NTPW * 16);
    int gr = lane >> 2, gc = lane & 3;

    // prologue: first sub-tile's eaSb
    bf16x8 a0 = load16(eaSb + (size_t)(base + m) * 64 + q * 8);
    bf16x8 a1 = load16(eaSb + (size_t)(base + m) * 64 + 32 + q * 8);

    // register run-carry state (per lane, one open run per t-column-block)
    float carry[8];
#pragma unroll
    for (int t = 0; t < 8; t++) carry[t] = 0.f;
    int carryDst = -1;

    for (int it = 0; it < NTPW; ++it, base += 16) {
        // prefetch next sub-tile's eaSb
        bf16x8 a0n = a0, a1n = a1;
        if (it < NTPW - 1) {
            a0n = load16(eaSb + (size_t)(base + 16 + m) * 64 + q * 8);
            a1n = load16(eaSb + (size_t)(base + 16 + m) * 64 + 32 + q * 8);
        }
        // current meta (L2-hot sequential)
        int d_r = dstS[base + m];
        int gsrc = srcS[base + gr];
        float Cj[4];
#pragma unroll
        for (int j = 0; j < 4; j++) Cj[j] = cS[base + q * 4 + j];
        int dstj[4];
#pragma unroll
        for (int j = 0; j < 4; j++) dstj[j] = __shfl(d_r, q * 4 + j);

        // early flush of carry if dst run ended (atomics hide under GEMMs)
        if (carryDst >= 0 && carryDst != dstj[0]) {
#pragma unroll
            for (int t = 0; t < 8; t++)
                unsafeAtomicAdd(&agg[(size_t)carryDst * 128 + t * 16 + m], carry[t]);
        }
        bool seed = (carryDst == dstj[0]);

        // --- GEMM1: registers only ---
        floatx4 acc[8];
#pragma unroll
        for (int t = 0; t < 8; t++) {
            floatx4 z = (floatx4){0.f, 0.f, 0.f, 0.f};
            z = __builtin_amdgcn_mfma_f32_16x16x32_bf16(a0, w1lo[t], z, 0, 0, 0);
            acc[t] = __builtin_amdgcn_mfma_f32_16x16x32_bf16(a1, w1hi[t], z, 0, 0, 0);
        }

        // --- ssp + P write ---
#pragma unroll
        for (int t = 0; t < 8; t++) {
            int c = t * 16 + m;
#pragma unroll
            for (int j = 0; j < 4; j++)
                P[w][q * 4 + j][c] = f2bf(sspf(acc[t][j] + b1v[t]));
        }

        // --- issue xf gathers (land under GEMM2) ---
        const uint4* gs = (const uint4*)&xfb[(size_t)gsrc * 128 + gc * 32];
        uint4 x0 = gs[0], x1 = gs[1], x2 = gs[2], x3 = gs[3];

        // --- GEMM2: P (LDS) x w2L (LDS, swizzled) ---
        floatx4 acc2[8];
#pragma unroll
        for (int t = 0; t < 8; t++) acc2[t] = (floatx4){0.f, 0.f, 0.f, 0.f};
#pragma unroll
        for (int k0 = 0; k0 < 128; k0 += 32) {
            FragU fa; fa.q = *(const uint4*)&P[w][m][k0 + q * 8];
#pragma unroll
            for (int t = 0; t < 8; t++) {
                int n = t * 16 + m;
                int bo = n * 256 + ((((k0 + q * 8) * 2)) ^ ((n & 7) << 4));
                bf16x8 b = load16((const unsigned short*)(w2L + bo));
                acc2[t] = __builtin_amdgcn_mfma_f32_16x16x32_bf16(fa.v, b, acc2[t], 0, 0, 0);
            }
        }

        // park staged xf rows in P (after this wave's GEMM2 reads)
        {
            uint4* dptr = (uint4*)&P[w][gr][gc * 32];
            dptr[0] = x0; dptr[1] = x1; dptr[2] = x2; dptr[3] = x3;
        }

        // --- epilogue: msg = (eh + b2) * C * xf[src]; run-combine by dst in registers ---
#pragma unroll
        for (int t = 0; t < 8; t++) {
            int c = t * 16 + m;
            float bb = b2v[t];
            float v4[4];
#pragma unroll
            for (int j = 0; j < 4; j++)
                v4[j] = (acc2[t][j] + bb) * Cj[j] * bf2f(P[w][q * 4 + j][c]);
            float run = seed ? (carry[t] + v4[0]) : v4[0];
#pragma unroll
            for (int j = 1; j < 4; j++) {
                if (dstj[j] == dstj[j - 1]) run += v4[j];
                else {
                    unsafeAtomicAdd(&agg[(size_t)dstj[j - 1] * 128 + c], run);
                    run = v4[j];
                }
            }
            carry[t] = run;   // open run for dstj[3], carried to next sub-tile
        }
        carryDst = dstj[3];

        a0 = a0n; a1 = a1n;
    }

    // final flush
#pragma unroll
    for (int t = 0; t < 8; t++)
        unsafeAtomicAdd(&agg[(size_t)carryDst * 128 + t * 16 + m], carry[t]);
}

// ---------------- kE2 (fallback when workspace too small for eaSb) ----------------
__global__ __launch_bounds__(256) void kE2(const float* __restrict__ ea,
                                           const unsigned short* __restrict__ w1b,
                                           const float* __restrict__ b1,
                                           const unsigned short* __restrict__ w2b,
                                           const float* __restrict__ b2,
                                           const int* __restrict__ ePerm,
                                           const int* __restrict__ dstS,
                                           const int* __restrict__ srcS,
                                           const float* __restrict__ cS,
                                           const unsigned short* __restrict__ xfb,
                                           float* __restrict__ agg) {
    __shared__ __align__(16) unsigned short P[64][136];
    __shared__ float accS[64][132];
    __shared__ int sSlot[64];
    __shared__ int sSlotDst[64];
    __shared__ int sD;

    int tid = threadIdx.x;
    int lane = tid & 63;
    int wave = tid >> 6;
    int m = lane & 15, q = lane >> 4;
    int base = blockIdx.x * 64;

    float* accFlat = &accS[0][0];
    for (int i = tid; i < 64 * 132; i += 256) accFlat[i] = 0.f;

    if (tid < 64) {
        int i = tid;
        int di = dstS[base + i];
        bool flag = (i == 0) || (di != dstS[base + i - 1]);
        unsigned long long bm = __ballot(flag ? 1 : 0);
        unsigned long long low = (i == 63) ? ~0ull : ((1ull << (i + 1)) - 1ull);
        int slot = (int)__popcll(bm & low) - 1;
        sSlot[i] = slot;
        if (flag) sSlotDst[slot] = di;
        if (i == 63) sD = slot + 1;
    }

    int eRow = ePerm[base + wave * 16 + m];

    floatx4 acc[8];
#pragma unroll
    for (int t = 0; t < 8; t++) acc[t] = (floatx4){0.f, 0.f, 0.f, 0.f};
    {
        bf16x8 a = f8frag(ea + (size_t)eRow * 50 + q * 8);
#pragma unroll
        for (int t = 0; t < 8; t++) {
            int n = t * 16 + m;
            bf16x8 b = loaddw(w1b + (size_t)n * 50 + q * 8);
            acc[t] = __builtin_amdgcn_mfma_f32_16x16x32_bf16(a, b, acc[t], 0, 0, 0);
        }
    }
    {
        int kbase = 32 + q * 8;
        FragU fa;
        const float* pa = ea + (size_t)eRow * 50 + kbase;
#pragma unroll
        for (int j = 0; j < 8; j++) fa.u[j] = (kbase + j < 50) ? f2bf(pa[j]) : 0;
#pragma unroll
        for (int t = 0; t < 8; t++) {
            int n = t * 16 + m;
            FragU fb;
            const unsigned int* pb = (const unsigned int*)(w1b + (size_t)n * 50 + kbase);
#pragma unroll
            for (int t2 = 0; t2 < 4; t2++) fb.d[t2] = (kbase + 2 * t2 < 50) ? pb[t2] : 0u;
            acc[t] = __builtin_amdgcn_mfma_f32_16x16x32_bf16(fa.v, fb.v, acc[t], 0, 0, 0);
        }
    }
#pragma unroll
    for (int t = 0; t < 8; t++) {
        int c = t * 16 + m;
        float bb = b1[c];
#pragma unroll
        for (int j = 0; j < 4; j++)
            P[wave * 16 + q * 4 + j][c] = f2bf(sspf(acc[t][j] + bb));
    }
    __syncthreads();

    floatx4 acc2[8];
#pragma unroll
    for (int t = 0; t < 8; t++) acc2[t] = (floatx4){0.f, 0.f, 0.f, 0.f};
#pragma unroll
    for (int k0 = 0; k0 < 128; k0 += 32) {
        FragU fa; fa.q = *(const uint4*)&P[wave * 16 + m][k0 + q * 8];
#pragma unroll
        for (int t = 0; t < 8; t++) {
            int n = t * 16 + m;
            bf16x8 b = load16(w2b + (size_t)n * 128 + k0 + q * 8);
            acc2[t] = __builtin_amdgcn_mfma_f32_16x16x32_bf16(fa.v, b, acc2[t], 0, 0, 0);
        }
    }

    int sl[4], srcj[4]; float Cj[4];
#pragma unroll
    for (int j = 0; j < 4; j++) {
        int r = wave * 16 + q * 4 + j;
        int g = base + r;
        sl[j] = sSlot[r];
        Cj[j] = cS[g];
        srcj[j] = srcS[g];
    }
#pragma unroll
    for (int t = 0; t < 8; t++) {
        int c = t * 16 + m;
        float bb = b2[c];
        float v4[4];
#pragma unroll
        for (int j = 0; j < 4; j++)
            v4[j] = (acc2[t][j] + bb) * Cj[j] * bf2f(xfb[(size_t)srcj[j] * 128 + c]);
        float run = v4[0];
#pragma unroll
        for (int j = 1; j < 4; j++) {
            if (sl[j] == sl[j - 1]) run += v4[j];
            else { atomicAdd(&accS[sl[j - 1]][c], run); run = v4[j]; }
        }
        atomicAdd(&accS[sl[3]][c], run);
    }
    __syncthreads();

    int D = sD;
    for (int idx = tid; idx < D * 128; idx += 256) {
        int s = idx >> 7, c = idx & 127;
        unsafeAtomicAdd(&agg[(size_t)sSlotDst[s] * 128 + c], accS[s][c]);
    }
}

// ---------------- kC: xc = conv_lin2(agg); h = h2 + ssp(xc); pooling ----------------
__global__ __launch_bounds__(256) void kC(const float* __restrict__ agg,
                                          const unsigned short* __restrict__ wb,
                                          const float* __restrict__ b,
                                          const unsigned short* __restrict__ h2b,
                                          unsigned short* __restrict__ hnb,
                                          const int* __restrict__ batch,
                                          float* __restrict__ pool,
                                          int doPool) {
    int lane = threadIdx.x & 63;
    int wave = threadIdx.x >> 6;
    int m = lane & 15, q = lane >> 4;
    int rowBase = blockIdx.x * 64 + wave * 16;
    int arow = rowBase + m;
    int arowc = (arow < NN) ? arow : (NN - 1);

    floatx4 acc[8];
#pragma unroll
    for (int t = 0; t < 8; t++) acc[t] = (floatx4){0.f, 0.f, 0.f, 0.f};

#pragma unroll
    for (int k0 = 0; k0 < 128; k0 += 32) {
        bf16x8 fa = f8frag(agg + (size_t)arowc * 128 + k0 + q * 8);
#pragma unroll
        for (int t = 0; t < 8; t++) {
            int n = t * 16 + m;
            bf16x8 bfr = load16(wb + (size_t)n * 128 + k0 + q * 8);
            acc[t] = __builtin_amdgcn_mfma_f32_16x16x32_bf16(fa, bfr, acc[t], 0, 0, 0);
        }
    }

    int r0 = rowBase + q * 4;
    float vsum[4] = {0.f, 0.f, 0.f, 0.f};
#pragma unroll
    for (int t = 0; t < 8; t++) {
        int c = t * 16 + m;
        float bb = b[c];
#pragma unroll
        for (int j = 0; j < 4; j++) {
            int r = r0 + j; int rc = (r < NN) ? r : (NN - 1);
            float v = bf2f(h2b[(size_t)rc * 128 + c]) + sspf(acc[t][j] + bb);
            if (r < NN) {
                hnb[(size_t)r * 128 + c] = f2bf(v);
                vsum[j] += v;
            }
        }
    }
    if (doPool) {
#pragma unroll
        for (int j = 0; j < 4; j++) {
            float v = vsum[j];
#pragma unroll
            for (int off = 1; off < 16; off <<= 1) v += __shfl_xor(v, off, 16);
            int r = r0 + j;
            if (m == 0 && r < NN) unsafeAtomicAdd(&pool[clampi(batch[r], BB - 1)], v);
        }
    }
}

// ---------------- kS ----------------
__global__ __launch_bounds__(256) void kS(const float* __restrict__ pool,
                                          const int* __restrict__ counts,
                                          float* __restrict__ stateBuf) {
    int b = threadIdx.x;
    if (b < BB) {
        float c = (float)counts[b];
        c = (c < 1.f) ? 1.f : c;
        float v = pool[b] / c;
        stateBuf[b * 2 + 0] = v;
        stateBuf[b * 2 + 1] = v;
    }
}

// ---------------- kOut ----------------
__global__ __launch_bounds__(256) void kOut(const unsigned short* __restrict__ hnb,
                                            const unsigned short* __restrict__ owb,
                                            const float* __restrict__ ob,
                                            float* __restrict__ out) {
    int lane = threadIdx.x & 63;
    int wave = threadIdx.x >> 6;
    int m = lane & 15, q = lane >> 4;
    int rowBase = blockIdx.x * 64 + wave * 16;
    int arow = rowBase + m;
    int arowc = (arow < NN) ? arow : (NN - 1);

    floatx4 acc[8];
#pragma unroll
    for (int t = 0; t < 8; t++) acc[t] = (floatx4){0.f, 0.f, 0.f, 0.f};
#pragma unroll
    for (int k0 = 0; k0 < 128; k0 += 32) {
        bf16x8 a = load16(hnb + (size_t)arowc * 128 + k0 + q * 8);
#pragma unroll
        for (int t = 0; t < 8; t++) {
            int n = t * 16 + m;
            bf16x8 bfr = load16(owb + (size_t)n * 128 + k0 + q * 8);
            acc[t] = __builtin_amdgcn_mfma_f32_16x16x32_bf16(a, bfr, acc[t], 0, 0, 0);
        }
    }
    int r0 = rowBase + q * 4;
#pragma unroll
    for (int t = 0; t < 8; t++) {
        int c = t * 16 + m;
        float bb = ob[c];
#pragma unroll
        for (int j = 0; j < 4; j++) {
            int r = r0 + j;
            if (r < NN) out[(size_t)r * 128 + c] = acc[t][j] + bb;
        }
    }
}

extern "C" void kernel_launch(void* const* d_in, const int* in_sizes, int n_in,
                              void* d_out, int out_size, void* d_ws, size_t ws_size,
                              hipStream_t stream) {
    const float* h     = (const float*)d_in[0];
    const float* ew    = (const float*)d_in[1];
    const float* ea    = (const float*)d_in[2];
    const float* sa    = (const float*)d_in[3];
    const float* lin1w = (const float*)d_in[4];
    const float* lin1b = (const float*)d_in[5];
    const float* mw1   = (const float*)d_in[6];
    const float* mb1   = (const float*)d_in[7];
    const float* mw2   = (const float*)d_in[8];
    const float* mb2   = (const float*)d_in[9];
    const float* c1w   = (const float*)d_in[10];
    const float* c2w   = (const float*)d_in[11];
    const float* c2b   = (const float*)d_in[12];
    const float* outw  = (const float*)d_in[13];
    const float* outb  = (const float*)d_in[14];
    const int* eidx    = (const int*)d_in[15];
    const int* batch   = (const int*)d_in[16];
    float* out = (float*)d_out;

    char* ws = (char*)d_ws;
    unsigned short* hnb   = (unsigned short*)(ws);              // 12.8 MB
    unsigned short* h2b   = (unsigned short*)(ws + 12800000);   // 12.8 MB
    unsigned short* xfb   = (unsigned short*)(ws + 25600000);   // 12.8 MB
    float*          agg   = (float*)(ws + 38400000);            // 25.6 MB
    int*            pos   = (int*)(ws + 64000000);              // 3.2 MB
    int*            ePerm = (int*)(ws + 67200000);              // 3.2 MB (fallback only)
    int*            dstS  = (int*)(ws + 70400000);              // 3.2 MB
    int*            srcS  = (int*)(ws + 73600000);              // 3.2 MB
    float*          cS    = (float*)(ws + 76800000);            // 3.2 MB
    int*            cnt   = (int*)(ws + 80000000);              // 200 KB
    int*            off   = (int*)(ws + 80200000);              // 200 KB
    int*            cur   = (int*)(ws + 80400000);              // 200 KB
    int*            blkSum= (int*)(ws + 80600000);              // 256 B
    unsigned short* wb    = (unsigned short*)(ws + 80600512);   // 354,304 B (177152 ushorts)
    float*          pool  = (float*)(ws + 80954816);
    int*            counts= (int*)(ws + 80955840);
    float*          stateBuf = (float*)(ws + 80956864);
    const size_t EAOFF = 80958912;                              // 16B aligned
    unsigned short* eaSb = (unsigned short*)(ws + EAOFF);       // 102.4 MB

    const size_t need = EAOFF + (size_t)EE * 64 * 2;
    const int useF = (ws_size >= need) ? 1 : 0;

    // bf16 weight banks
    unsigned short* mw1b = wb;            // [2][128][50]   (fallback kE2)
    unsigned short* mw2b = wb + 12800;    // [2][128][128]
    unsigned short* c1wb = wb + 45568;    // [2][128][128]
    unsigned short* c2wb = wb + 78336;    // [2][128][128]
    unsigned short* l1wb = wb + 111104;   // [2][128][130]
    unsigned short* owb  = wb + 144384;   // [128][128]
    unsigned short* w1pb = wb + 160768;   // [2][128][64]  zero-padded mlp_w1

    hipMemsetAsync(cnt, 0, NN * 4, stream);
    hipMemsetAsync(cur, 0, NN * 4, stream);
    hipMemsetAsync(counts, 0, BB * 4, stream);
    hipMemsetAsync(pool, 0, BB * 4, stream);

    kPrep<<<(NN + 255) / 256, 256, 0, stream>>>(batch, counts, sa, stateBuf);
    kHist<<<1024, 256, 0, stream>>>(eidx, cnt);
    kScanA<<<(NN + 1023) / 1024, 1024, 0, stream>>>(cnt, off, blkSum);
    kScanB<<<1, 64, 0, stream>>>(blkSum, (NN + 1023) / 1024);
    kScanC<<<(NN + 255) / 256, 256, 0, stream>>>(off, blkSum);
    kScatter<<<1024, 256, 0, stream>>>(eidx, ew, off, cur, pos, ePerm, dstS, srcS, cS);

    kConvW<<<177152 / 256, 256, 0, stream>>>(mw1, mw2, c1w, c2w, lin1w, outw, wb);
    kConv<<<4096, 256, 0, stream>>>(h, hnb, NN * 128);
    if (useF) {
        kPermEA<<<(EE * 4) / 256, 256, 0, stream>>>(ea, pos, eaSb);   // once: ea constant over layers
    }

    const int gridN = (NN + 63) / 64;   // 782

    for (int i = 0; i < 2; i++) {
        hipMemsetAsync(agg, 0, (size_t)NN * 128 * 4, stream);
        kA<<<gridN, 256, 0, stream>>>(hnb,
                                      l1wb + (size_t)i * 128 * 130,
                                      lin1w + (size_t)i * 128 * 130,
                                      lin1b + (size_t)i * 128,
                                      c1wb + (size_t)i * 128 * 128,
                                      stateBuf, batch, h2b, xfb);
        if (useF) {
            kF<<<KFBLK, 256, 0, stream>>>(eaSb,
                                          w1pb + (size_t)i * 128 * 64,
                                          mb1 + (size_t)i * 128,
                                          mw2b + (size_t)i * 128 * 128,
                                          mb2 + (size_t)i * 128,
                                          dstS, srcS, cS, xfb, agg);
        } else {
            kE2<<<EE / 64, 256, 0, stream>>>(ea,
                                             mw1b + (size_t)i * 128 * 50,
                                             mb1 + (size_t)i * 128,
                                             mw2b + (size_t)i * 128 * 128,
                                             mb2 + (size_t)i * 128,
                                             ePerm, dstS, srcS, cS, xfb, agg);
        }
        kC<<<gridN, 256, 0, stream>>>(agg,
                                      c2wb + (size_t)i * 128 * 128,
                                      c2b + (size_t)i * 128,
                                      h2b, hnb, batch, pool, (i == 0) ? 1 : 0);
        if (i == 0) kS<<<1, 256, 0, stream>>>(pool, counts, stateBuf);
    }
    kOut<<<gridN, 256, 0, stream>>>(hnb, owb, outb, out);
}